// Round 11
// baseline (315.206 us; speedup 1.0000x reference)
//
#include <hip/hip_runtime.h>
#include <hip/hip_bf16.h>
#include <cstdint>

// ---------------------------------------------------------------------------
// FullHeteroGCN: 2-layer hetero GraphSAGE (mean aggr).
// R11: agg restructure — one 16-lane group per ROW (4 rows/wave, no
// cross-group reduce), degree-sorted row permutation per 128-dst bucket
// (bitonic in bucket_build) so co-scheduled rows have equal degree;
// f32x2 (v_pk_add_f32) accumulation; padding infra removed.
// R10 post-mortem: -25% instr -> only -9% time; epilogue reduce + fixed
// per-row costs were the remaining structural fat.
// CSR build: bucket radix-partition. Activations bf16 (cvt_pk RNE);
// weights hi/lo split-bf16 (2 MFMA/tile), XOR-swizzled LDS staging.
// ---------------------------------------------------------------------------

typedef __attribute__((ext_vector_type(8))) short bf16x8;
typedef __attribute__((ext_vector_type(4))) float f32x4;
typedef __attribute__((ext_vector_type(2))) float f32x2;

#define HB 2048          // max total buckets (LDS arrays); totB = 1564 here
#define BCAP 6144        // bucket_build col staging capacity

__device__ __forceinline__ void gload_lds16(const void* g, void* l) {
    __builtin_amdgcn_global_load_lds(
        (const __attribute__((address_space(1))) unsigned int*)g,
        (__attribute__((address_space(3))) unsigned int*)l,
        16, 0, 0);
}
__device__ __forceinline__ f32x4 mfma16(bf16x8 a, bf16x8 b, f32x4 c) {
    return __builtin_amdgcn_mfma_f32_16x16x32_bf16(a, b, c, 0, 0, 0);
}
// packed f32->bf16 RNE, one instruction (src0 -> low half)
__device__ __forceinline__ uint32_t cvtpk(float lo, float hi) {
    uint32_t r;
    asm("v_cvt_pk_bf16_f32 %0, %1, %2" : "=v"(r) : "v"(lo), "v"(hi));
    return r;
}
__device__ __forceinline__ unsigned short bf16_1(float v) {
    uint32_t r;
    asm("v_cvt_pk_bf16_f32 %0, %1, %2" : "=v"(r) : "v"(v), "v"(v));
    return (unsigned short)r;
}
__device__ __forceinline__ float blo(uint32_t v) { return __uint_as_float(v << 16); }
__device__ __forceinline__ float bhi(uint32_t v) { return __uint_as_float(v & 0xFFFF0000u); }

// ======================= CSR build (bucket partition) =======================

__global__ __launch_bounds__(256)
void bucket_scan_kernel(const int* __restrict__ bcnt, int nbc, int nba, int nbh,
                        int Ec, int Ea, int Eh,
                        int* __restrict__ gboff, int* __restrict__ bcur) {
    const int r  = blockIdx.x;
    const int sb = (r == 0) ? 0 : (r == 1) ? nbc : nbc + nba;
    const int nb = (r == 0) ? nbc : (r == 1) ? nba : nbh;
    const int base = (r == 0) ? 0 : (r == 1) ? Ec : Ec + Ea;
    const int tid = threadIdx.x;
    __shared__ int sm[256];
    __shared__ int carry;
    if (tid == 0) carry = base;
    __syncthreads();
    for (int c0 = 0; c0 < nb; c0 += 256) {
        int i = c0 + tid;
        int v = (i < nb) ? bcnt[sb + i] : 0;
        sm[tid] = v; __syncthreads();
        for (int d = 1; d < 256; d <<= 1) {
            int t = (tid >= d) ? sm[tid - d] : 0;
            __syncthreads();
            sm[tid] += t;
            __syncthreads();
        }
        int pre = carry + sm[tid] - v;
        if (i < nb) { gboff[sb + i] = pre; bcur[sb + i] = pre; }
        int tot = sm[255];
        __syncthreads();
        if (tid == 0) carry += tot;
        __syncthreads();
    }
    if (tid == 0 && r == 2) gboff[nbc + nba + nbh] = Ec + Ea + Eh;
}

__global__ __launch_bounds__(256)
void partition_kernel(const int* __restrict__ sc, const int* __restrict__ dc, int Ec,
                      const int* __restrict__ sa, const int* __restrict__ da, int Ea,
                      const int* __restrict__ sh, const int* __restrict__ dh, int Eh,
                      int nbc, int nba, int totB,
                      int* __restrict__ bcur, uint2* __restrict__ pairs) {
    __shared__ int lbin[HB];
    __shared__ int gbase[HB];
    __shared__ int swork[256];
    __shared__ uint2 sorted[2048];
    __shared__ unsigned short sbin[2048];
    const int tid = threadIdx.x;
    const int Etot = Ec + Ea + Eh;
    const int start = blockIdx.x * 2048;
    const int cnt = min(2048, Etot - start);
    for (int b = tid; b < HB; b += 256) lbin[b] = 0;
    __syncthreads();
    uint32_t esrc[8], edst[8]; int ebin[8];
#pragma unroll
    for (int k = 0; k < 8; ++k) {
        int i = start + k * 256 + tid;
        int bin = -1; uint32_t s = 0, d = 0;
        if (i < Etot) {
            if (i < Ec)           { s = sc[i];           d = dc[i];           bin = (int)(d >> 7); }
            else if (i < Ec + Ea) { s = sa[i - Ec];      d = da[i - Ec];      bin = nbc + (int)(d >> 7); }
            else                  { s = sh[i - Ec - Ea]; d = dh[i - Ec - Ea]; bin = nbc + nba + (int)(d >> 7); }
            atomicAdd(&lbin[bin], 1);
        }
        esrc[k] = s; edst[k] = d; ebin[k] = bin;
    }
    __syncthreads();
    const int base8 = tid * 8;
    int lv[8]; int s0 = 0;
#pragma unroll
    for (int j = 0; j < 8; ++j) { lv[j] = lbin[base8 + j]; s0 += lv[j]; }
    swork[tid] = s0; __syncthreads();
    for (int d = 1; d < 256; d <<= 1) {
        int t = (tid >= d) ? swork[tid - d] : 0;
        __syncthreads();
        swork[tid] += t;
        __syncthreads();
    }
    int run = swork[tid] - s0;
    __syncthreads();
#pragma unroll
    for (int j = 0; j < 8; ++j) { lbin[base8 + j] = run; run += lv[j]; }
    __syncthreads();
    for (int b = tid; b < totB; b += 256) {
        int off = lbin[b];
        int c = lbin[b + 1] - off;
        if (c > 0) gbase[b] = atomicAdd(&bcur[b], c) - off;
    }
    __syncthreads();
#pragma unroll
    for (int k = 0; k < 8; ++k) {
        if (ebin[k] >= 0) {
            int p = atomicAdd(&lbin[ebin[k]], 1);
            sorted[p] = make_uint2(esrc[k], edst[k]);
            sbin[p] = (unsigned short)ebin[k];
        }
    }
    __syncthreads();
    for (int p = tid; p < cnt; p += 256)
        pairs[gbase[sbin[p]] + p] = sorted[p];
}

// One block per bucket (<=128 dsts): LDS count -> scan -> packed off|deg;
// bitonic degree-sort -> row permutation; LDS scatter -> coalesced col write.
__global__ __launch_bounds__(256)
void bucket_build_kernel(const uint2* __restrict__ pairs,
                         const int* __restrict__ gboff,
                         int nbc, int nba,
                         int NP, int NA, int Ec, int Ea,
                         uint32_t* __restrict__ off_c, uint32_t* __restrict__ off_a,
                         uint32_t* __restrict__ off_h,
                         int* __restrict__ col_c, int* __restrict__ col_a,
                         int* __restrict__ col_h,
                         int* __restrict__ perm_c, int* __restrict__ perm_a,
                         int* __restrict__ perm_h) {
    const int bin = blockIdx.x;
    int lb, relbase, n; uint32_t* off; int* colp; int* permp;
    if (bin < nbc)            { lb = bin;             relbase = 0;       n = NP; off = off_c; colp = col_c; permp = perm_c; }
    else if (bin < nbc + nba) { lb = bin - nbc;       relbase = Ec;      n = NP; off = off_a; colp = col_a; permp = perm_a; }
    else                      { lb = bin - nbc - nba; relbase = Ec + Ea; n = NA; off = off_h; colp = col_h; permp = perm_h; }
    const int d0 = lb << 7;
    const int e0 = gboff[bin], e1 = gboff[bin + 1];
    const int cnt = e1 - e0;
    const int tid = threadIdx.x;
    const int valid = min(128, n - d0);
    __shared__ int lcnt[128];
    __shared__ int lcur[128];
    __shared__ int skey[128];
    __shared__ int sidx[128];
    __shared__ int colbuf[BCAP];
    if (tid < 128) lcnt[tid] = 0;
    __syncthreads();
    for (int e = e0 + tid; e < e1; e += 256)
        atomicAdd(&lcnt[(int)pairs[e].y - d0], 1);
    __syncthreads();
    int myc = 0;
    if (tid < 128) {
        myc = lcnt[tid];
        skey[tid] = (tid < valid) ? myc : 0x7FFFFFFF;
        sidx[tid] = tid;
    }
    __syncthreads();
    // inclusive scan of lcnt (original dst order)
    for (int d = 1; d < 128; d <<= 1) {
        int t = (tid < 128 && tid >= d) ? lcnt[tid - d] : 0;
        __syncthreads();
        if (tid < 128) lcnt[tid] += t;
        __syncthreads();
    }
    if (tid < 128) {
        int excl = lcnt[tid] - myc;
        lcur[tid] = excl;
        if (tid < valid)
            off[d0 + tid] = (uint32_t)(e0 - relbase + excl) | ((uint32_t)myc << 22);
    }
    // bitonic sort by degree (ascending; sentinels at end)
    for (int k = 2; k <= 128; k <<= 1) {
        for (int j = k >> 1; j > 0; j >>= 1) {
            __syncthreads();
            if (tid < 128) {
                int l2 = tid ^ j;
                if (l2 > tid) {
                    bool up = ((tid & k) == 0);
                    int k0 = skey[tid], k1 = skey[l2];
                    if (up ? (k0 > k1) : (k0 < k1)) {
                        skey[tid] = k1; skey[l2] = k0;
                        int s = sidx[tid]; sidx[tid] = sidx[l2]; sidx[l2] = s;
                    }
                }
            }
        }
    }
    __syncthreads();
    if (tid < valid) permp[d0 + tid] = d0 + sidx[tid];
    // scatter col (compact, unpadded)
    if (cnt <= BCAP) {
        for (int e = e0 + tid; e < e1; e += 256) {
            uint2 pr = pairs[e];
            int p = atomicAdd(&lcur[(int)pr.y - d0], 1);
            colbuf[p] = (int)pr.x;
        }
        __syncthreads();
        for (int i = tid; i < cnt; i += 256) colp[(e0 - relbase) + i] = colbuf[i];
    } else {
        for (int e = e0 + tid; e < e1; e += 256) {
            uint2 pr = pairs[e];
            int p = atomicAdd(&lcur[(int)pr.y - d0], 1);
            colp[(e0 - relbase) + p] = (int)pr.x;
        }
    }
}

// ======================= prologue (cvt + prep + hist) ==========

__device__ __forceinline__ void split_store(float w, unsigned short* hi,
                                            unsigned short* lo, int i) {
    uint32_t u = __float_as_uint(w);
    hi[i] = (unsigned short)(u >> 16);
    float l = w - __uint_as_float(u & 0xFFFF0000u);
    lo[i] = (unsigned short)(__float_as_uint(l) >> 16);
}

__global__ __launch_bounds__(256)
void prologue_kernel(const float* __restrict__ x_p, const float* __restrict__ x_a,
                     uint32_t* __restrict__ xb_p, uint32_t* __restrict__ xb_a,
                     int NP, int NA, int nbCvt,
                     const float* l1cWl, const float* l1cbl, const float* l1cWr,
                     const float* l1aWl, const float* l1abl, const float* l1aWr,
                     const float* l2cWl, const float* l2cbl, const float* l2cWr,
                     const float* l2aWl, const float* l2abl, const float* l2aWr,
                     const float* lhWl, const float* lhWr,
                     unsigned short* W1hi, unsigned short* W1lo, float* b1,
                     unsigned short* W2hi, unsigned short* W2lo, float* b2,
                     unsigned short* WHhi, unsigned short* WHlo,
                     const int* __restrict__ dc, int Ec,
                     const int* __restrict__ da, int Ea,
                     const int* __restrict__ dh, int Eh,
                     int nbc, int nba, int totB, int* __restrict__ bcnt) {
    __shared__ int lh[HB];
    const int b = blockIdx.x, tid = threadIdx.x;
    if (b < nbCvt) {
        int i = b * 256 + tid;
        const float* X; uint32_t* Y; int j;
        const int n80 = NP * 16;
        if (i < n80)                 { X = x_p; Y = xb_p; j = i; }
        else if (i < n80 + NA * 16)  { X = x_a; Y = xb_a; j = i - n80; }
        else return;
        float4 v0 = *(const float4*)(X + (size_t)j * 8);
        float4 v1 = *(const float4*)(X + (size_t)j * 8 + 4);
        uint4 o;
        o.x = cvtpk(v0.x, v0.y); o.y = cvtpk(v0.z, v0.w);
        o.z = cvtpk(v1.x, v1.y); o.w = cvtpk(v1.z, v1.w);
        *(uint4*)(Y + (size_t)j * 4) = o;
    } else if (b < nbCvt + 192) {
        const int bid = b - nbCvt;
        if (bid < 64) {
            int i = bid * 256 + tid;
            split_store(0.5f * l1cWl[i], W1hi, W1lo, i);
            split_store(0.5f * l1aWl[i], W1hi, W1lo, 16384 + i);
            split_store(0.5f * (l1cWr[i] + l1aWr[i]), W1hi, W1lo, 32768 + i);
            if (i < 128) b1[i] = 0.5f * (l1cbl[i] + l1abl[i]);
        } else if (bid < 128) {
            int i = (bid - 64) * 256 + tid;
            split_store(0.5f * l2cWl[i], W2hi, W2lo, i);
            split_store(0.5f * l2aWl[i], W2hi, W2lo, 16384 + i);
            split_store(0.5f * (l2cWr[i] + l2aWr[i]), W2hi, W2lo, 32768 + i);
            if (i < 128) b2[i] = 0.5f * (l2cbl[i] + l2abl[i]);
        } else {
            int i = (bid - 128) * 256 + tid;
            split_store(lhWl[i], WHhi, WHlo, i);
            split_store(lhWr[i], WHhi, WHlo, 16384 + i);
        }
    } else {
        // bucket histogram via LDS
        const int hb = b - nbCvt - 192;
        for (int k = tid; k < HB; k += 256) lh[k] = 0;
        __syncthreads();
        const int Etot = Ec + Ea + Eh;
        const int start = hb * 16384;
        const int end = min(start + 16384, Etot);
        for (int i = start + tid; i < end; i += 256) {
            int bin;
            if (i < Ec)            bin = dc[i] >> 7;
            else if (i < Ec + Ea)  bin = nbc + (da[i - Ec] >> 7);
            else                   bin = nbc + nba + (dh[i - Ec - Ea] >> 7);
            atomicAdd(&lh[bin], 1);
        }
        __syncthreads();
        for (int k = tid; k < totB; k += 256) {
            int v = lh[k];
            if (v) atomicAdd(&bcnt[k], v);
        }
    }
}

// ======================= aggregation =======================

__device__ __forceinline__ void acc4(f32x2* a, uint4 q) {
    a[0] += (f32x2){blo(q.x), bhi(q.x)};
    a[1] += (f32x2){blo(q.y), bhi(q.y)};
    a[2] += (f32x2){blo(q.z), bhi(q.z)};
    a[3] += (f32x2){blo(q.w), bhi(q.w)};
}

// 4 rows per wave: group g (16 lanes) owns one full row (256 B) and its
// whole edge list. Degree-sorted perm makes the 4 rows near-equal-degree:
// shared scalar loop bound, group-uniform predication, no cross-group reduce.
__device__ __forceinline__ void agg_row4(const uint32_t* __restrict__ X,
                                         const uint32_t* __restrict__ offp,
                                         const int* __restrict__ col,
                                         const int* __restrict__ perm,
                                         uint32_t* __restrict__ Y,
                                         int rbase, int nrows) {
    const int lane = threadIdx.x & 63;
    const int g = lane >> 4, t = lane & 15;
    int r = rbase + g; if (r >= nrows) r = nrows - 1;
    const int rp = perm[r];
    const uint32_t pk = offp[rp];
    const int e = (int)(pk & 0x3FFFFFu);
    const int deg = (int)(pk >> 22);
    int m = deg;
    m = max(m, __shfl_xor(m, 16, 64));
    m = max(m, __shfl_xor(m, 32, 64));
    const int nit = __builtin_amdgcn_readfirstlane(m);
    const char* Xc = (const char*)X;
    const uint32_t bo = (uint32_t)(t << 4);
    f32x2 A0[4] = {{0.f,0.f},{0.f,0.f},{0.f,0.f},{0.f,0.f}};
    f32x2 A1[4] = {{0.f,0.f},{0.f,0.f},{0.f,0.f},{0.f,0.f}};
    int i = 0;
    for (; i + 2 <= nit; i += 2) {
        uint4 q0, q1;
        const bool p0 = i < deg, p1 = (i + 1) < deg;
        if (p0) { int s = col[e + i];     q0 = *(const uint4*)(Xc + (((uint32_t)s << 8) + bo)); }
        if (p1) { int s = col[e + i + 1]; q1 = *(const uint4*)(Xc + (((uint32_t)s << 8) + bo)); }
        if (p0) acc4(A0, q0);
        if (p1) acc4(A1, q1);
    }
    if (i < nit && i < deg) {
        int s = col[e + i];
        uint4 q = *(const uint4*)(Xc + (((uint32_t)s << 8) + bo));
        acc4(A0, q);
    }
    const float inv = 1.0f / (float)(deg > 0 ? deg : 1);
    f32x2 v0 = A0[0] + A1[0], v1 = A0[1] + A1[1];
    f32x2 v2 = A0[2] + A1[2], v3 = A0[3] + A1[3];
    uint4 o;
    o.x = cvtpk(v0.x * inv, v0.y * inv); o.y = cvtpk(v1.x * inv, v1.y * inv);
    o.z = cvtpk(v2.x * inv, v2.y * inv); o.w = cvtpk(v3.x * inv, v3.y * inv);
    *(uint4*)(Y + (size_t)rp * 64 + (t << 2)) = o;
}

__global__ __launch_bounds__(256)
void agg_l1_kernel(const uint32_t* __restrict__ xb_p, const uint32_t* __restrict__ xb_a,
                   const uint32_t* __restrict__ off_c, const int* __restrict__ col_c,
                   const uint32_t* __restrict__ off_a, const int* __restrict__ col_a,
                   const uint32_t* __restrict__ off_h, const int* __restrict__ col_h,
                   const int* __restrict__ perm_c, const int* __restrict__ perm_a,
                   const int* __restrict__ perm_h,
                   uint32_t* __restrict__ S1, uint32_t* __restrict__ S2,
                   uint32_t* __restrict__ SH, int NP, int NA) {
    int rb = ((blockIdx.x * 256 + threadIdx.x) >> 6) * 4;
    if (rb < NP)               agg_row4(xb_p, off_c, col_c, perm_c, S1, rb, NP);
    else if (rb < 2 * NP)      agg_row4(xb_a, off_a, col_a, perm_a, S2, rb - NP, NP);
    else if (rb < 2 * NP + NA) agg_row4(xb_p, off_h, col_h, perm_h, SH, rb - 2 * NP, NA);
}

__global__ __launch_bounds__(256)
void agg_l2_kernel(const uint32_t* __restrict__ P1, const uint32_t* __restrict__ A1,
                   const uint32_t* __restrict__ off_c, const int* __restrict__ col_c,
                   const uint32_t* __restrict__ off_a, const int* __restrict__ col_a,
                   const int* __restrict__ perm_c, const int* __restrict__ perm_a,
                   uint32_t* __restrict__ S2, uint32_t* __restrict__ S3, int NP) {
    int rb = ((blockIdx.x * 256 + threadIdx.x) >> 6) * 4;
    if (rb < NP)          agg_row4(P1, off_c, col_c, perm_c, S2, rb, NP);
    else if (rb < 2 * NP) agg_row4(A1, off_a, col_a, perm_a, S3, rb - NP, NP);
}

// ======================= transform (split-bf16 MFMA) =======================

template <int PAIRS>
__device__ __forceinline__ void transform_body(
        int blk, const unsigned short* A0, const unsigned short* A1,
        const unsigned short* A2,
        const unsigned short* __restrict__ Whi, const unsigned short* __restrict__ Wlo,
        const float* __restrict__ bias, unsigned short* Y, int N,
        unsigned short* Bhi, unsigned short* Blo) {
    const int tid  = threadIdx.x;
    const int l    = tid & 63;
    const int wv   = tid >> 6;
    const int lrow = l & 15;
    const int lkg  = l >> 4;
    const int rw   = blk * 128 + wv * 32;

    f32x4 acc0[8], acc1[8];
#pragma unroll
    for (int t = 0; t < 8; ++t) {
        acc0[t] = (f32x4){0.f, 0.f, 0.f, 0.f};
        acc1[t] = (f32x4){0.f, 0.f, 0.f, 0.f};
    }

    int arow0 = rw + lrow;      if (arow0 >= N) arow0 = N - 1;
    int arow1 = rw + 16 + lrow; if (arow1 >= N) arow1 = N - 1;
    const int kbase = lkg << 3;
    const int cb    = lkg << 4;

#pragma unroll 1
    for (int p = 0; p < PAIRS; ++p) {
        {
            const char* srcH = (const char*)(Whi + (p << 14));
            const char* srcL = (const char*)(Wlo + (p << 14));
#pragma unroll
            for (int it = 0; it < 8; ++it) {
                const int L = it * 4096 + tid * 16;
                const int j = L >> 8;
                const int g = (j << 8) + ((L & 255) ^ ((j & 7) << 4));
                gload_lds16(srcH + g, (char*)Bhi + L);
                gload_lds16(srcL + g, (char*)Blo + L);
            }
        }
        __syncthreads();
        const unsigned short* A = (p == 0) ? A0 : (p == 1) ? A1 : A2;
#pragma unroll
        for (int kc = 0; kc < 4; ++kc) {
            bf16x8 a0 = *(const bf16x8*)(A + (size_t)arow0 * 128 + kc * 32 + kbase);
            bf16x8 a1 = *(const bf16x8*)(A + (size_t)arow1 * 128 + kc * 32 + kbase);
            const int cbk = kc * 64 + cb;
#pragma unroll
            for (int t = 0; t < 8; ++t) {
                const int jt   = (t << 4) + lrow;
                const int addr = (jt << 8) + (cbk ^ ((jt & 7) << 4));
                bf16x8 bh = *(const bf16x8*)((const char*)Bhi + addr);
                bf16x8 bl = *(const bf16x8*)((const char*)Blo + addr);
                acc0[t] = mfma16(a0, bh, acc0[t]);
                acc1[t] = mfma16(a1, bh, acc1[t]);
                acc0[t] = mfma16(a0, bl, acc0[t]);
                acc1[t] = mfma16(a1, bl, acc1[t]);
            }
        }
        __syncthreads();
    }
#pragma unroll
    for (int t = 0; t < 8; ++t) {
        const int c = t * 16 + lrow;
        const float bv = bias[c];
#pragma unroll
        for (int r = 0; r < 4; ++r) {
            int row0 = rw + (lkg << 2) + r;
            if (row0 < N)
                Y[(size_t)row0 * 128 + c] = bf16_1(fmaxf(acc0[t][r] + bv, 0.f));
            int row1 = row0 + 16;
            if (row1 < N)
                Y[(size_t)row1 * 128 + c] = bf16_1(fmaxf(acc1[t][r] + bv, 0.f));
        }
    }
}

__global__ __launch_bounds__(256, 2)
void transform_l1_kernel(const unsigned short* S1, const unsigned short* S2,
                         const unsigned short* xb_p,
                         const unsigned short* __restrict__ W1hi,
                         const unsigned short* __restrict__ W1lo,
                         const float* __restrict__ b1,
                         const unsigned short* SH, const unsigned short* xb_a,
                         const unsigned short* __restrict__ WHhi,
                         const unsigned short* __restrict__ WHlo,
                         const float* __restrict__ bh,
                         unsigned short* P1out, unsigned short* A1out,
                         int NP, int NA, int nbP) {
    __shared__ unsigned short Bhi[128 * 128];
    __shared__ unsigned short Blo[128 * 128];
    if ((int)blockIdx.x < nbP)
        transform_body<3>(blockIdx.x, S1, S2, xb_p, W1hi, W1lo, b1,
                          P1out, NP, Bhi, Blo);
    else
        transform_body<2>(blockIdx.x - nbP, SH, xb_a, nullptr, WHhi, WHlo, bh,
                          A1out, NA, Bhi, Blo);
}

__global__ __launch_bounds__(256, 2)
void transform_p2_kernel(const unsigned short* A0, const unsigned short* A1,
                         const unsigned short* A2,
                         const unsigned short* __restrict__ Whi,
                         const unsigned short* __restrict__ Wlo,
                         const float* __restrict__ bias, unsigned short* Y, int N) {
    __shared__ unsigned short Bhi[128 * 128];
    __shared__ unsigned short Blo[128 * 128];
    transform_body<3>(blockIdx.x, A0, A1, A2, Whi, Wlo, bias, Y, N, Bhi, Blo);
}

__global__ __launch_bounds__(256)
void final_linear_kernel(const uint32_t* __restrict__ P, const float* __restrict__ Wt,
                         const float* __restrict__ bb, float* __restrict__ out, int N) {
    __shared__ float lw[1024];
    __shared__ float lb[8];
    for (int i = threadIdx.x; i < 1024; i += 256) lw[i] = Wt[i];
    if (threadIdx.x < 8) lb[threadIdx.x] = bb[threadIdx.x];
    __syncthreads();
    int idx = blockIdx.x * 256 + threadIdx.x;
    if (idx >= N * 8) return;
    int row = idx >> 3, c = idx & 7;
    const uint32_t* pr = P + (size_t)row * 64;
    const float* wr = &lw[c << 7];
    float s = 0.f;
#pragma unroll
    for (int k = 0; k < 64; k += 4) {
        uint4 q = *(const uint4*)(pr + k);
        const float* w = wr + (k << 1);
        s += blo(q.x) * w[0] + bhi(q.x) * w[1]
           + blo(q.y) * w[2] + bhi(q.y) * w[3]
           + blo(q.z) * w[4] + bhi(q.z) * w[5]
           + blo(q.w) * w[6] + bhi(q.w) * w[7];
    }
    out[idx] = s + lb[c];
}

extern "C" void kernel_launch(void* const* d_in, const int* in_sizes, int n_in,
                              void* d_out, int out_size, void* d_ws, size_t ws_size,
                              hipStream_t stream) {
    const float* x_p = (const float*)d_in[0];
    const float* x_a = (const float*)d_in[1];
    const int* c_src = (const int*)d_in[2];
    const int* c_dst = (const int*)d_in[3];
    const int* a_src = (const int*)d_in[4];
    const int* a_dst = (const int*)d_in[5];
    const int* h_src = (const int*)d_in[6];
    const int* h_dst = (const int*)d_in[7];
    const float* l1c_Wl = (const float*)d_in[8];
    const float* l1c_bl = (const float*)d_in[9];
    const float* l1c_Wr = (const float*)d_in[10];
    const float* l1a_Wl = (const float*)d_in[11];
    const float* l1a_bl = (const float*)d_in[12];
    const float* l1a_Wr = (const float*)d_in[13];
    const float* l1h_Wl = (const float*)d_in[14];
    const float* l1h_bl = (const float*)d_in[15];
    const float* l1h_Wr = (const float*)d_in[16];
    const float* l2c_Wl = (const float*)d_in[17];
    const float* l2c_bl = (const float*)d_in[18];
    const float* l2c_Wr = (const float*)d_in[19];
    const float* l2a_Wl = (const float*)d_in[20];
    const float* l2a_bl = (const float*)d_in[21];
    const float* l2a_Wr = (const float*)d_in[22];
    const float* linW   = (const float*)d_in[26];
    const float* linb   = (const float*)d_in[27];

    const int NP = in_sizes[0] / 128;
    const int NA = in_sizes[1] / 128;
    const int Ec = in_sizes[2];
    const int Ea = in_sizes[4];
    const int Eh = in_sizes[6];
    const int Etot = Ec + Ea + Eh;

    const int nbc = (NP + 127) >> 7;
    const int nba = (NP + 127) >> 7;
    const int nbh = (NA + 127) >> 7;
    const int totB = nbc + nba + nbh;
    if (totB > HB) return;

    // ---- carve workspace ----
    char* base = (char*)d_ws;
    size_t cur = 0;
    auto carve = [&](size_t bytes) -> char* {
        char* p = base + cur;
        cur = (cur + bytes + 255) & ~(size_t)255;
        return p;
    };
    uint32_t* xb_p = (uint32_t*)carve((size_t)(NP + 1) * 128 * 2);
    uint32_t* xb_a = (uint32_t*)carve((size_t)(NA + 1) * 128 * 2);
    uint32_t* S1 = (uint32_t*)carve((size_t)(NP + 1) * 128 * 2);
    uint32_t* S2 = (uint32_t*)carve((size_t)NP * 128 * 2);
    uint32_t* S3 = (uint32_t*)carve((size_t)NP * 128 * 2);
    uint32_t* SH = (uint32_t*)carve((size_t)(NA + 1) * 128 * 2);
    unsigned short* W1hi = (unsigned short*)carve(3 * 16384 * 2);
    unsigned short* W1lo = (unsigned short*)carve(3 * 16384 * 2);
    unsigned short* W2hi = (unsigned short*)carve(3 * 16384 * 2);
    unsigned short* W2lo = (unsigned short*)carve(3 * 16384 * 2);
    unsigned short* WHhi = (unsigned short*)carve(2 * 16384 * 2);
    unsigned short* WHlo = (unsigned short*)carve(2 * 16384 * 2);
    float* b1 = (float*)carve(512);
    float* b2 = (float*)carve(512);
    uint32_t* off_c = (uint32_t*)carve((size_t)NP * 4);
    uint32_t* off_a = (uint32_t*)carve((size_t)NP * 4);
    uint32_t* off_h = (uint32_t*)carve((size_t)NA * 4);
    int* perm_c = (int*)carve((size_t)NP * 4);
    int* perm_a = (int*)carve((size_t)NP * 4);
    int* perm_h = (int*)carve((size_t)NA * 4);
    int* colAll = (int*)carve(((size_t)Etot + 256) * 4);
    uint2* pairs = (uint2*)carve((size_t)Etot * 8);
    int* gboff = (int*)carve((size_t)(totB + 1) * 4);
    int* bcur  = (int*)carve((size_t)totB * 4);
    int* bcnt  = (int*)carve((size_t)totB * 4);
    if (cur > ws_size) return;

    int* col_c = colAll;
    int* col_a = colAll + Ec;
    int* col_h = colAll + Ec + Ea;

    // ---- prologue: memset + {cvt, prep, hist} in one dispatch ----
    hipMemsetAsync(bcnt, 0, (size_t)totB * 4, stream);
    const int nbCvt = ((NP + NA) * 16 + 255) / 256;
    const int nbHist = (Etot + 16383) / 16384;
    prologue_kernel<<<nbCvt + 192 + nbHist, 256, 0, stream>>>(
        x_p, x_a, xb_p, xb_a, NP, NA, nbCvt,
        l1c_Wl, l1c_bl, l1c_Wr, l1a_Wl, l1a_bl, l1a_Wr,
        l2c_Wl, l2c_bl, l2c_Wr, l2a_Wl, l2a_bl, l2a_Wr,
        l1h_Wl, l1h_Wr, W1hi, W1lo, b1, W2hi, W2lo, b2, WHhi, WHlo,
        c_dst, Ec, a_dst, Ea, h_dst, Eh, nbc, nba, totB, bcnt);

    // ---- CSR build (compact col, packed off|deg, degree-sorted perm) ----
    bucket_scan_kernel<<<3, 256, 0, stream>>>(bcnt, nbc, nba, nbh, Ec, Ea, Eh,
                                              gboff, bcur);
    partition_kernel<<<(Etot + 2047) / 2048, 256, 0, stream>>>(
        c_src, c_dst, Ec, a_src, a_dst, Ea, h_src, h_dst, Eh,
        nbc, nba, totB, bcur, pairs);
    bucket_build_kernel<<<totB, 256, 0, stream>>>(
        pairs, gboff, nbc, nba, NP, NA, Ec, Ea,
        off_c, off_a, off_h, col_c, col_a, col_h, perm_c, perm_a, perm_h);

    // ---- layer 1 ----
    const int rows_l1 = 2 * NP + NA;
    agg_l1_kernel<<<(rows_l1 + 15) / 16, 256, 0, stream>>>(
        xb_p, xb_a, off_c, col_c, off_a, col_a, off_h, col_h,
        perm_c, perm_a, perm_h, S1, S2, SH, NP, NA);
    const int nbP = (NP + 127) / 128;
    const int nbA = (NA + 127) / 128;
    transform_l1_kernel<<<nbP + nbA, 256, 0, stream>>>(
        (const unsigned short*)S1, (const unsigned short*)S2,
        (const unsigned short*)xb_p, W1hi, W1lo, b1,
        (const unsigned short*)SH, (const unsigned short*)xb_a, WHhi, WHlo, l1h_bl,
        (unsigned short*)S1, (unsigned short*)SH, NP, NA, nbP);

    // ---- layer 2 ----
    agg_l2_kernel<<<(2 * NP + 15) / 16, 256, 0, stream>>>(
        S1, SH, off_c, col_c, off_a, col_a, perm_c, perm_a, S2, S3, NP);
    transform_p2_kernel<<<nbP, 256, 0, stream>>>(
        (const unsigned short*)S2, (const unsigned short*)S3,
        (const unsigned short*)S1, W2hi, W2lo, b2,
        (unsigned short*)S2, NP);

    // ---- head ----
    final_linear_kernel<<<((NP * 8) + 255) / 256, 256, 0, stream>>>(
        S2, linW, linb, (float*)d_out, NP);
}

// Round 12
// 276.700 us; speedup vs baseline: 1.1392x; 1.1392x over previous
//
#include <hip/hip_runtime.h>
#include <hip/hip_bf16.h>
#include <cstdint>

// ---------------------------------------------------------------------------
// FullHeteroGCN: 2-layer hetero GraphSAGE (mean aggr).
// R12: consolidation. R11's group-per-row agg + degree sort was a regression
// (agg unchanged at 74us — random-gather service bound — but CSR sort added
// cost). Revert agg/CSR to R10 (best: 292us). New: classifier head fused
// into transform_p2 epilogue (in-register bias+relu, LDS-staged linW dot,
// 16-lane shfl_xor reduce) — removes final_linear kernel and the 25MB p2
// store+reload.
// Activations bf16 (cvt_pk RNE); padded CSR (zero-row pads, off|deg packed);
// weights hi/lo split-bf16 (2 MFMA/tile), XOR-swizzled LDS staging.
// ---------------------------------------------------------------------------

typedef __attribute__((ext_vector_type(8))) short bf16x8;
typedef __attribute__((ext_vector_type(4))) float f32x4;

#define HB 2048          // max total buckets (LDS arrays); totB = 1564 here
#define BCAP 6144        // bucket_build col staging capacity (padded edges)

__device__ __forceinline__ void gload_lds16(const void* g, void* l) {
    __builtin_amdgcn_global_load_lds(
        (const __attribute__((address_space(1))) unsigned int*)g,
        (__attribute__((address_space(3))) unsigned int*)l,
        16, 0, 0);
}
__device__ __forceinline__ f32x4 mfma16(bf16x8 a, bf16x8 b, f32x4 c) {
    return __builtin_amdgcn_mfma_f32_16x16x32_bf16(a, b, c, 0, 0, 0);
}
// packed f32->bf16 RNE, one instruction
__device__ __forceinline__ uint32_t cvtpk(float lo, float hi) {
    uint32_t r;
    asm("v_cvt_pk_bf16_f32 %0, %1, %2" : "=v"(r) : "v"(lo), "v"(hi));
    return r;
}
__device__ __forceinline__ unsigned short bf16_1(float v) {
    uint32_t r;
    asm("v_cvt_pk_bf16_f32 %0, %1, %2" : "=v"(r) : "v"(v), "v"(v));
    return (unsigned short)r;
}
__device__ __forceinline__ float blo(uint32_t v) { return __uint_as_float(v << 16); }
__device__ __forceinline__ float bhi(uint32_t v) { return __uint_as_float(v & 0xFFFF0000u); }

// ======================= CSR build (bucket partition) =======================

__global__ __launch_bounds__(256)
void bucket_scan_kernel(const int* __restrict__ bcnt, int nbc, int nba, int nbh,
                        int Ec, int Ea, int Eh,
                        int* __restrict__ gboff, int* __restrict__ bcur) {
    const int r  = blockIdx.x;
    const int sb = (r == 0) ? 0 : (r == 1) ? nbc : nbc + nba;
    const int nb = (r == 0) ? nbc : (r == 1) ? nba : nbh;
    const int base = (r == 0) ? 0 : (r == 1) ? Ec : Ec + Ea;
    const int tid = threadIdx.x;
    __shared__ int sm[256];
    __shared__ int carry;
    if (tid == 0) carry = base;
    __syncthreads();
    for (int c0 = 0; c0 < nb; c0 += 256) {
        int i = c0 + tid;
        int v = (i < nb) ? bcnt[sb + i] : 0;
        sm[tid] = v; __syncthreads();
        for (int d = 1; d < 256; d <<= 1) {
            int t = (tid >= d) ? sm[tid - d] : 0;
            __syncthreads();
            sm[tid] += t;
            __syncthreads();
        }
        int pre = carry + sm[tid] - v;
        if (i < nb) { gboff[sb + i] = pre; bcur[sb + i] = pre; }
        int tot = sm[255];
        __syncthreads();
        if (tid == 0) carry += tot;
        __syncthreads();
    }
    if (tid == 0 && r == 2) gboff[nbc + nba + nbh] = Ec + Ea + Eh;
}

__global__ __launch_bounds__(256)
void partition_kernel(const int* __restrict__ sc, const int* __restrict__ dc, int Ec,
                      const int* __restrict__ sa, const int* __restrict__ da, int Ea,
                      const int* __restrict__ sh, const int* __restrict__ dh, int Eh,
                      int nbc, int nba, int totB,
                      int* __restrict__ bcur, uint2* __restrict__ pairs) {
    __shared__ int lbin[HB];
    __shared__ int gbase[HB];
    __shared__ int swork[256];
    __shared__ uint2 sorted[2048];
    __shared__ unsigned short sbin[2048];
    const int tid = threadIdx.x;
    const int Etot = Ec + Ea + Eh;
    const int start = blockIdx.x * 2048;
    const int cnt = min(2048, Etot - start);
    for (int b = tid; b < HB; b += 256) lbin[b] = 0;
    __syncthreads();
    uint32_t esrc[8], edst[8]; int ebin[8];
#pragma unroll
    for (int k = 0; k < 8; ++k) {
        int i = start + k * 256 + tid;
        int bin = -1; uint32_t s = 0, d = 0;
        if (i < Etot) {
            if (i < Ec)           { s = sc[i];           d = dc[i];           bin = (int)(d >> 7); }
            else if (i < Ec + Ea) { s = sa[i - Ec];      d = da[i - Ec];      bin = nbc + (int)(d >> 7); }
            else                  { s = sh[i - Ec - Ea]; d = dh[i - Ec - Ea]; bin = nbc + nba + (int)(d >> 7); }
            atomicAdd(&lbin[bin], 1);
        }
        esrc[k] = s; edst[k] = d; ebin[k] = bin;
    }
    __syncthreads();
    const int base8 = tid * 8;
    int lv[8]; int s0 = 0;
#pragma unroll
    for (int j = 0; j < 8; ++j) { lv[j] = lbin[base8 + j]; s0 += lv[j]; }
    swork[tid] = s0; __syncthreads();
    for (int d = 1; d < 256; d <<= 1) {
        int t = (tid >= d) ? swork[tid - d] : 0;
        __syncthreads();
        swork[tid] += t;
        __syncthreads();
    }
    int run = swork[tid] - s0;
    __syncthreads();
#pragma unroll
    for (int j = 0; j < 8; ++j) { lbin[base8 + j] = run; run += lv[j]; }
    __syncthreads();
    for (int b = tid; b < totB; b += 256) {
        int off = lbin[b];
        int c = lbin[b + 1] - off;
        if (c > 0) gbase[b] = atomicAdd(&bcur[b], c) - off;
    }
    __syncthreads();
#pragma unroll
    for (int k = 0; k < 8; ++k) {
        if (ebin[k] >= 0) {
            int p = atomicAdd(&lbin[ebin[k]], 1);
            sorted[p] = make_uint2(esrc[k], edst[k]);
            sbin[p] = (unsigned short)ebin[k];
        }
    }
    __syncthreads();
    for (int p = tid; p < cnt; p += 256)
        pairs[gbase[sbin[p]] + p] = sorted[p];
}

// One block per bucket (<=128 dsts): LDS count -> padded scan -> packed
// off|deg write; colbuf pre-filled with zero-row index; scatter; coalesced
// col write. Padded layout: bucket base = (e0-relbase) + 384*lb.
__global__ __launch_bounds__(256)
void bucket_build_kernel(const uint2* __restrict__ pairs,
                         const int* __restrict__ gboff,
                         int nbc, int nba,
                         int NP, int NA, int Ec, int Ea,
                         uint32_t* __restrict__ off_c, uint32_t* __restrict__ off_a,
                         uint32_t* __restrict__ off_h,
                         int* __restrict__ col_c, int* __restrict__ col_a,
                         int* __restrict__ col_h) {
    const int bin = blockIdx.x;
    int lb, relbase, n, zrow; uint32_t* off; int* colp;
    if (bin < nbc)            { lb = bin;             relbase = 0;       n = NP; zrow = NP; off = off_c; colp = col_c; }
    else if (bin < nbc + nba) { lb = bin - nbc;       relbase = Ec;      n = NP; zrow = NA; off = off_a; colp = col_a; }
    else                      { lb = bin - nbc - nba; relbase = Ec + Ea; n = NA; zrow = NP; off = off_h; colp = col_h; }
    const int d0 = lb << 7;
    const int e0 = gboff[bin], e1 = gboff[bin + 1];
    const int padBase = (e0 - relbase) + lb * 384;
    const int tid = threadIdx.x;
    __shared__ int lcnt[128];
    __shared__ int lcur[128];
    __shared__ int colbuf[BCAP];
    if (tid < 128) lcnt[tid] = 0;
    __syncthreads();
    for (int e = e0 + tid; e < e1; e += 256)
        atomicAdd(&lcnt[(int)pairs[e].y - d0], 1);
    __syncthreads();
    int c = 0, pc = 0;
    if (tid < 128) { c = lcnt[tid]; pc = (c + 3) & ~3; lcnt[tid] = pc; }
    __syncthreads();
    for (int d = 1; d < 128; d <<= 1) {
        int t = (tid < 128 && tid >= d) ? lcnt[tid - d] : 0;
        __syncthreads();
        if (tid < 128) lcnt[tid] += t;
        __syncthreads();
    }
    if (tid < 128) {
        int excl = lcnt[tid] - pc;
        lcur[tid] = excl;
        int d = d0 + tid;
        if (d < n) off[d] = (uint32_t)(padBase + excl) | ((uint32_t)c << 22);
    }
    __syncthreads();
    const int cntPad = lcnt[127];
    if (cntPad <= BCAP) {
        for (int i = tid; i < cntPad; i += 256) colbuf[i] = zrow;
        __syncthreads();
        for (int e = e0 + tid; e < e1; e += 256) {
            uint2 pr = pairs[e];
            int p = atomicAdd(&lcur[(int)pr.y - d0], 1);
            colbuf[p] = (int)pr.x;
        }
        __syncthreads();
        for (int i = tid; i < cntPad; i += 256) colp[padBase + i] = colbuf[i];
    } else {  // overflow fallback
        for (int i = tid; i < cntPad; i += 256) colp[padBase + i] = zrow;
        __syncthreads();
        for (int e = e0 + tid; e < e1; e += 256) {
            uint2 pr = pairs[e];
            int p = atomicAdd(&lcur[(int)pr.y - d0], 1);
            colp[padBase + p] = (int)pr.x;
        }
    }
}

// ======================= prologue (cvt + prep + hist + zero rows) ==========

__device__ __forceinline__ void split_store(float w, unsigned short* hi,
                                            unsigned short* lo, int i) {
    uint32_t u = __float_as_uint(w);
    hi[i] = (unsigned short)(u >> 16);
    float l = w - __uint_as_float(u & 0xFFFF0000u);
    lo[i] = (unsigned short)(__float_as_uint(l) >> 16);
}

__global__ __launch_bounds__(256)
void prologue_kernel(const float* __restrict__ x_p, const float* __restrict__ x_a,
                     uint32_t* __restrict__ xb_p, uint32_t* __restrict__ xb_a,
                     int NP, int NA, int nbCvt,
                     const float* l1cWl, const float* l1cbl, const float* l1cWr,
                     const float* l1aWl, const float* l1abl, const float* l1aWr,
                     const float* l2cWl, const float* l2cbl, const float* l2cWr,
                     const float* l2aWl, const float* l2abl, const float* l2aWr,
                     const float* lhWl, const float* lhWr,
                     unsigned short* W1hi, unsigned short* W1lo, float* b1,
                     unsigned short* W2hi, unsigned short* W2lo, float* b2,
                     unsigned short* WHhi, unsigned short* WHlo,
                     const int* __restrict__ dc, int Ec,
                     const int* __restrict__ da, int Ea,
                     const int* __restrict__ dh, int Eh,
                     int nbc, int nba, int totB, int* __restrict__ bcnt,
                     int nbHist, uint32_t* __restrict__ S1, uint32_t* __restrict__ SH) {
    __shared__ int lh[HB];
    const int b = blockIdx.x, tid = threadIdx.x;
    if (b < nbCvt) {
        int i = b * 256 + tid;
        const float* X; uint32_t* Y; int j;
        const int n80 = NP * 16;
        if (i < n80)                 { X = x_p; Y = xb_p; j = i; }
        else if (i < n80 + NA * 16)  { X = x_a; Y = xb_a; j = i - n80; }
        else return;
        float4 v0 = *(const float4*)(X + (size_t)j * 8);
        float4 v1 = *(const float4*)(X + (size_t)j * 8 + 4);
        uint4 o;
        o.x = cvtpk(v0.x, v0.y); o.y = cvtpk(v0.z, v0.w);
        o.z = cvtpk(v1.x, v1.y); o.w = cvtpk(v1.z, v1.w);
        *(uint4*)(Y + (size_t)j * 4) = o;
    } else if (b < nbCvt + 192) {
        const int bid = b - nbCvt;
        if (bid < 64) {
            int i = bid * 256 + tid;
            split_store(0.5f * l1cWl[i], W1hi, W1lo, i);
            split_store(0.5f * l1aWl[i], W1hi, W1lo, 16384 + i);
            split_store(0.5f * (l1cWr[i] + l1aWr[i]), W1hi, W1lo, 32768 + i);
            if (i < 128) b1[i] = 0.5f * (l1cbl[i] + l1abl[i]);
        } else if (bid < 128) {
            int i = (bid - 64) * 256 + tid;
            split_store(0.5f * l2cWl[i], W2hi, W2lo, i);
            split_store(0.5f * l2aWl[i], W2hi, W2lo, 16384 + i);
            split_store(0.5f * (l2cWr[i] + l2aWr[i]), W2hi, W2lo, 32768 + i);
            if (i < 128) b2[i] = 0.5f * (l2cbl[i] + l2abl[i]);
        } else {
            int i = (bid - 128) * 256 + tid;
            split_store(lhWl[i], WHhi, WHlo, i);
            split_store(lhWr[i], WHhi, WHlo, 16384 + i);
        }
    } else if (b < nbCvt + 192 + nbHist) {
        // bucket histogram via LDS
        const int hb = b - nbCvt - 192;
        for (int k = tid; k < HB; k += 256) lh[k] = 0;
        __syncthreads();
        const int Etot = Ec + Ea + Eh;
        const int start = hb * 16384;
        const int end = min(start + 16384, Etot);
        for (int i = start + tid; i < end; i += 256) {
            int bin;
            if (i < Ec)            bin = dc[i] >> 7;
            else if (i < Ec + Ea)  bin = nbc + (da[i - Ec] >> 7);
            else                   bin = nbc + nba + (dh[i - Ec - Ea] >> 7);
            atomicAdd(&lh[bin], 1);
        }
        __syncthreads();
        for (int k = tid; k < totB; k += 256) {
            int v = lh[k];
            if (v) atomicAdd(&bcnt[k], v);
        }
    } else {
        // zero rows at index N of each gathered table
        const int w = tid & 63, which = tid >> 6;
        uint32_t* dst = (which == 0) ? xb_p + (size_t)NP * 64
                      : (which == 1) ? xb_a + (size_t)NA * 64
                      : (which == 2) ? S1 + (size_t)NP * 64
                                     : SH + (size_t)NA * 64;
        dst[w] = 0;
    }
}

// ======================= aggregation =======================

__device__ __forceinline__ void acc8(float* a, uint4 q) {
    a[0] += blo(q.x); a[1] += bhi(q.x);
    a[2] += blo(q.y); a[3] += bhi(q.y);
    a[4] += blo(q.z); a[5] += bhi(q.z);
    a[6] += blo(q.w); a[7] += bhi(q.w);
}

// padded quad-edge gather mean: 1 wave/row; uniform quad count (no
// predication); 32-bit byte-offset gathers; cvt_pk epilogue.
__device__ __forceinline__ void agg_row(const uint32_t* __restrict__ X,
                                        const uint32_t* __restrict__ offp,
                                        const int* __restrict__ col,
                                        uint32_t* __restrict__ Y, int row) {
    const int lane = threadIdx.x & 63;
    const int g = lane >> 4, t = lane & 15;
    const uint32_t pk = offp[row];
    int e = (int)(pk & 0x3FFFFFu);
    const int deg = (int)(pk >> 22);
    int nq = (deg + 3) >> 2;
    const char* Xc = (const char*)X;
    const uint32_t bo = (uint32_t)(t << 4);
    float A0[8] = {0.f, 0.f, 0.f, 0.f, 0.f, 0.f, 0.f, 0.f};
    float A1[8] = {0.f, 0.f, 0.f, 0.f, 0.f, 0.f, 0.f, 0.f};
    while (nq >= 2) {
        int sA = col[e + g];
        int sB = col[e + 4 + g];
        uint4 qA = *(const uint4*)(Xc + (((uint32_t)sA << 8) + bo));
        uint4 qB = *(const uint4*)(Xc + (((uint32_t)sB << 8) + bo));
        acc8(A0, qA); acc8(A1, qB);
        e += 8; nq -= 2;
    }
    if (nq) {
        int sA = col[e + g];
        uint4 qA = *(const uint4*)(Xc + (((uint32_t)sA << 8) + bo));
        acc8(A0, qA);
    }
    const float inv = 1.0f / (float)(deg > 0 ? deg : 1);
    float a[8];
#pragma unroll
    for (int j = 0; j < 8; ++j) {
        float v = A0[j] + A1[j];
        v += __shfl_xor(v, 16, 64);
        v += __shfl_xor(v, 32, 64);
        a[j] = v * inv;
    }
    if (g == 0) {
        uint4 o;
        o.x = cvtpk(a[0], a[1]); o.y = cvtpk(a[2], a[3]);
        o.z = cvtpk(a[4], a[5]); o.w = cvtpk(a[6], a[7]);
        *(uint4*)(Y + (size_t)row * 64 + (t << 2)) = o;
    }
}

__global__ __launch_bounds__(256)
void agg_l1_kernel(const uint32_t* __restrict__ xb_p, const uint32_t* __restrict__ xb_a,
                   const uint32_t* __restrict__ off_c, const int* __restrict__ col_c,
                   const uint32_t* __restrict__ off_a, const int* __restrict__ col_a,
                   const uint32_t* __restrict__ off_h, const int* __restrict__ col_h,
                   uint32_t* __restrict__ S1, uint32_t* __restrict__ S2,
                   uint32_t* __restrict__ SH, int NP, int NA) {
    int gw = (blockIdx.x * 256 + threadIdx.x) >> 6;
    if (gw < NP)               agg_row(xb_p, off_c, col_c, S1, gw);
    else if (gw < 2 * NP)      agg_row(xb_a, off_a, col_a, S2, gw - NP);
    else if (gw < 2 * NP + NA) agg_row(xb_p, off_h, col_h, SH, gw - 2 * NP);
}

__global__ __launch_bounds__(256)
void agg_l2_kernel(const uint32_t* __restrict__ P1, const uint32_t* __restrict__ A1,
                   const uint32_t* __restrict__ off_c, const int* __restrict__ col_c,
                   const uint32_t* __restrict__ off_a, const int* __restrict__ col_a,
                   uint32_t* __restrict__ S2, uint32_t* __restrict__ S3, int NP) {
    int gw = (blockIdx.x * 256 + threadIdx.x) >> 6;
    if (gw < NP)          agg_row(P1, off_c, col_c, S2, gw);
    else if (gw < 2 * NP) agg_row(A1, off_a, col_a, S3, gw - NP);
}

// ======================= transform (split-bf16 MFMA) =======================

template <int PAIRS>
__device__ __forceinline__ void transform_body(
        int blk, const unsigned short* A0, const unsigned short* A1,
        const unsigned short* A2,
        const unsigned short* __restrict__ Whi, const unsigned short* __restrict__ Wlo,
        const float* __restrict__ bias, unsigned short* Y, int N,
        unsigned short* Bhi, unsigned short* Blo) {
    const int tid  = threadIdx.x;
    const int l    = tid & 63;
    const int wv   = tid >> 6;
    const int lrow = l & 15;
    const int lkg  = l >> 4;
    const int rw   = blk * 128 + wv * 32;

    f32x4 acc0[8], acc1[8];
#pragma unroll
    for (int t = 0; t < 8; ++t) {
        acc0[t] = (f32x4){0.f, 0.f, 0.f, 0.f};
        acc1[t] = (f32x4){0.f, 0.f, 0.f, 0.f};
    }

    int arow0 = rw + lrow;      if (arow0 >= N) arow0 = N - 1;
    int arow1 = rw + 16 + lrow; if (arow1 >= N) arow1 = N - 1;
    const int kbase = lkg << 3;
    const int cb    = lkg << 4;

#pragma unroll 1
    for (int p = 0; p < PAIRS; ++p) {
        {
            const char* srcH = (const char*)(Whi + (p << 14));
            const char* srcL = (const char*)(Wlo + (p << 14));
#pragma unroll
            for (int it = 0; it < 8; ++it) {
                const int L = it * 4096 + tid * 16;
                const int j = L >> 8;
                const int g = (j << 8) + ((L & 255) ^ ((j & 7) << 4));
                gload_lds16(srcH + g, (char*)Bhi + L);
                gload_lds16(srcL + g, (char*)Blo + L);
            }
        }
        __syncthreads();
        const unsigned short* A = (p == 0) ? A0 : (p == 1) ? A1 : A2;
#pragma unroll
        for (int kc = 0; kc < 4; ++kc) {
            bf16x8 a0 = *(const bf16x8*)(A + (size_t)arow0 * 128 + kc * 32 + kbase);
            bf16x8 a1 = *(const bf16x8*)(A + (size_t)arow1 * 128 + kc * 32 + kbase);
            const int cbk = kc * 64 + cb;
#pragma unroll
            for (int t = 0; t < 8; ++t) {
                const int jt   = (t << 4) + lrow;
                const int addr = (jt << 8) + (cbk ^ ((jt & 7) << 4));
                bf16x8 bh = *(const bf16x8*)((const char*)Bhi + addr);
                bf16x8 bl = *(const bf16x8*)((const char*)Blo + addr);
                acc0[t] = mfma16(a0, bh, acc0[t]);
                acc1[t] = mfma16(a1, bh, acc1[t]);
                acc0[t] = mfma16(a0, bl, acc0[t]);
                acc1[t] = mfma16(a1, bl, acc1[t]);
            }
        }
        __syncthreads();
    }
#pragma unroll
    for (int t = 0; t < 8; ++t) {
        const int c = t * 16 + lrow;
        const float bv = bias[c];
#pragma unroll
        for (int r = 0; r < 4; ++r) {
            int row0 = rw + (lkg << 2) + r;
            if (row0 < N)
                Y[(size_t)row0 * 128 + c] = bf16_1(fmaxf(acc0[t][r] + bv, 0.f));
            int row1 = row0 + 16;
            if (row1 < N)
                Y[(size_t)row1 * 128 + c] = bf16_1(fmaxf(acc1[t][r] + bv, 0.f));
        }
    }
}

__global__ __launch_bounds__(256, 2)
void transform_l1_kernel(const unsigned short* S1, const unsigned short* S2,
                         const unsigned short* xb_p,
                         const unsigned short* __restrict__ W1hi,
                         const unsigned short* __restrict__ W1lo,
                         const float* __restrict__ b1,
                         const unsigned short* SH, const unsigned short* xb_a,
                         const unsigned short* __restrict__ WHhi,
                         const unsigned short* __restrict__ WHlo,
                         const float* __restrict__ bh,
                         unsigned short* P1out, unsigned short* A1out,
                         int NP, int NA, int nbP) {
    __shared__ unsigned short Bhi[128 * 128];
    __shared__ unsigned short Blo[128 * 128];
    if ((int)blockIdx.x < nbP)
        transform_body<3>(blockIdx.x, S1, S2, xb_p, W1hi, W1lo, b1,
                          P1out, NP, Bhi, Blo);
    else
        transform_body<2>(blockIdx.x - nbP, SH, xb_a, nullptr, WHhi, WHlo, bh,
                          A1out, NA, Bhi, Blo);
}

// transform_p2 with FUSED classifier head: p2 = relu(sum_p A_p@W_p^T + b)
// stays in registers; out[row][cls] = p2[row,:] . linW[cls,:] + linb[cls]
// via LDS-staged linW and a 16-lane shfl_xor reduce. No p2 store.
__global__ __launch_bounds__(256, 2)
void transform_p2_head_kernel(const unsigned short* A0, const unsigned short* A1,
                              const unsigned short* A2,
                              const unsigned short* __restrict__ Whi,
                              const unsigned short* __restrict__ Wlo,
                              const float* __restrict__ bias,
                              const float* __restrict__ linW,
                              const float* __restrict__ linb,
                              float* __restrict__ out, int N) {
    __shared__ unsigned short Bhi[128 * 128];
    __shared__ unsigned short Blo[128 * 128];
    __shared__ float lwd[1024];   // linW [8][128]
    __shared__ float lbd[8];
    const int tid  = threadIdx.x;
    const int l    = tid & 63;
    const int wv   = tid >> 6;
    const int lrow = l & 15;
    const int lkg  = l >> 4;
    const int rw   = (int)blockIdx.x * 128 + wv * 32;

    // stage head weights (visible after the first p-loop __syncthreads)
    for (int i = tid; i < 1024; i += 256) lwd[i] = linW[i];
    if (tid < 8) lbd[tid] = linb[tid];

    f32x4 acc0[8], acc1[8];
#pragma unroll
    for (int t = 0; t < 8; ++t) {
        acc0[t] = (f32x4){0.f, 0.f, 0.f, 0.f};
        acc1[t] = (f32x4){0.f, 0.f, 0.f, 0.f};
    }

    int arow0 = rw + lrow;      if (arow0 >= N) arow0 = N - 1;
    int arow1 = rw + 16 + lrow; if (arow1 >= N) arow1 = N - 1;
    const int kbase = lkg << 3;
    const int cb    = lkg << 4;

#pragma unroll 1
    for (int p = 0; p < 3; ++p) {
        {
            const char* srcH = (const char*)(Whi + (p << 14));
            const char* srcL = (const char*)(Wlo + (p << 14));
#pragma unroll
            for (int it = 0; it < 8; ++it) {
                const int L = it * 4096 + tid * 16;
                const int j = L >> 8;
                const int g = (j << 8) + ((L & 255) ^ ((j & 7) << 4));
                gload_lds16(srcH + g, (char*)Bhi + L);
                gload_lds16(srcL + g, (char*)Blo + L);
            }
        }
        __syncthreads();
        const unsigned short* A = (p == 0) ? A0 : (p == 1) ? A1 : A2;
#pragma unroll
        for (int kc = 0; kc < 4; ++kc) {
            bf16x8 a0 = *(const bf16x8*)(A + (size_t)arow0 * 128 + kc * 32 + kbase);
            bf16x8 a1 = *(const bf16x8*)(A + (size_t)arow1 * 128 + kc * 32 + kbase);
            const int cbk = kc * 64 + cb;
#pragma unroll
            for (int t = 0; t < 8; ++t) {
                const int jt   = (t << 4) + lrow;
                const int addr = (jt << 8) + (cbk ^ ((jt & 7) << 4));
                bf16x8 bh = *(const bf16x8*)((const char*)Bhi + addr);
                bf16x8 bl = *(const bf16x8*)((const char*)Blo + addr);
                acc0[t] = mfma16(a0, bh, acc0[t]);
                acc1[t] = mfma16(a1, bh, acc1[t]);
                acc0[t] = mfma16(a0, bl, acc0[t]);
                acc1[t] = mfma16(a1, bl, acc1[t]);
            }
        }
        __syncthreads();
    }
    // bias + relu in-register -> p2
#pragma unroll
    for (int t = 0; t < 8; ++t) {
        const float bv = bias[t * 16 + lrow];
#pragma unroll
        for (int r = 0; r < 4; ++r) {
            acc0[t][r] = fmaxf(acc0[t][r] + bv, 0.f);
            acc1[t][r] = fmaxf(acc1[t][r] + bv, 0.f);
        }
    }
    // head: per class, dot owned cols then reduce across the 16-lane group
    float o0[4], o1[4];
#pragma unroll
    for (int cls = 0; cls < 8; ++cls) {
        float wvv[8];
#pragma unroll
        for (int t = 0; t < 8; ++t) wvv[t] = lwd[cls * 128 + t * 16 + lrow];
#pragma unroll
        for (int r = 0; r < 4; ++r) {
            float s0 = 0.f, s1 = 0.f;
#pragma unroll
            for (int t = 0; t < 8; ++t) {
                s0 += acc0[t][r] * wvv[t];
                s1 += acc1[t][r] * wvv[t];
            }
            s0 += __shfl_xor(s0, 1, 64); s0 += __shfl_xor(s0, 2, 64);
            s0 += __shfl_xor(s0, 4, 64); s0 += __shfl_xor(s0, 8, 64);
            s1 += __shfl_xor(s1, 1, 64); s1 += __shfl_xor(s1, 2, 64);
            s1 += __shfl_xor(s1, 4, 64); s1 += __shfl_xor(s1, 8, 64);
            if (lrow == cls) { o0[r] = s0; o1[r] = s1; }
        }
    }
    if (lrow < 8) {
        const float lbv = lbd[lrow];
#pragma unroll
        for (int r = 0; r < 4; ++r) {
            int row0 = rw + (lkg << 2) + r;
            if (row0 < N) out[(size_t)row0 * 8 + lrow] = o0[r] + lbv;
            int row1 = row0 + 16;
            if (row1 < N) out[(size_t)row1 * 8 + lrow] = o1[r] + lbv;
        }
    }
}

extern "C" void kernel_launch(void* const* d_in, const int* in_sizes, int n_in,
                              void* d_out, int out_size, void* d_ws, size_t ws_size,
                              hipStream_t stream) {
    const float* x_p = (const float*)d_in[0];
    const float* x_a = (const float*)d_in[1];
    const int* c_src = (const int*)d_in[2];
    const int* c_dst = (const int*)d_in[3];
    const int* a_src = (const int*)d_in[4];
    const int* a_dst = (const int*)d_in[5];
    const int* h_src = (const int*)d_in[6];
    const int* h_dst = (const int*)d_in[7];
    const float* l1c_Wl = (const float*)d_in[8];
    const float* l1c_bl = (const float*)d_in[9];
    const float* l1c_Wr = (const float*)d_in[10];
    const float* l1a_Wl = (const float*)d_in[11];
    const float* l1a_bl = (const float*)d_in[12];
    const float* l1a_Wr = (const float*)d_in[13];
    const float* l1h_Wl = (const float*)d_in[14];
    const float* l1h_bl = (const float*)d_in[15];
    const float* l1h_Wr = (const float*)d_in[16];
    const float* l2c_Wl = (const float*)d_in[17];
    const float* l2c_bl = (const float*)d_in[18];
    const float* l2c_Wr = (const float*)d_in[19];
    const float* l2a_Wl = (const float*)d_in[20];
    const float* l2a_bl = (const float*)d_in[21];
    const float* l2a_Wr = (const float*)d_in[22];
    const float* linW   = (const float*)d_in[26];
    const float* linb   = (const float*)d_in[27];

    const int NP = in_sizes[0] / 128;
    const int NA = in_sizes[1] / 128;
    const int Ec = in_sizes[2];
    const int Ea = in_sizes[4];
    const int Eh = in_sizes[6];
    const int Etot = Ec + Ea + Eh;

    const int nbc = (NP + 127) >> 7;
    const int nba = (NP + 127) >> 7;
    const int nbh = (NA + 127) >> 7;
    const int totB = nbc + nba + nbh;
    if (totB > HB) return;

    // ---- carve workspace ----
    char* base = (char*)d_ws;
    size_t cur = 0;
    auto carve = [&](size_t bytes) -> char* {
        char* p = base + cur;
        cur = (cur + bytes + 255) & ~(size_t)255;
        return p;
    };
    uint32_t* xb_p = (uint32_t*)carve((size_t)(NP + 1) * 128 * 2);  // +zero row
    uint32_t* xb_a = (uint32_t*)carve((size_t)(NA + 1) * 128 * 2);  // +zero row
    uint32_t* S1 = (uint32_t*)carve((size_t)(NP + 1) * 128 * 2);    // +zero row
    uint32_t* S2 = (uint32_t*)carve((size_t)NP * 128 * 2);
    uint32_t* S3 = (uint32_t*)carve((size_t)NP * 128 * 2);
    uint32_t* SH = (uint32_t*)carve((size_t)(NA + 1) * 128 * 2);    // +zero row
    unsigned short* W1hi = (unsigned short*)carve(3 * 16384 * 2);
    unsigned short* W1lo = (unsigned short*)carve(3 * 16384 * 2);
    unsigned short* W2hi = (unsigned short*)carve(3 * 16384 * 2);
    unsigned short* W2lo = (unsigned short*)carve(3 * 16384 * 2);
    unsigned short* WHhi = (unsigned short*)carve(2 * 16384 * 2);
    unsigned short* WHlo = (unsigned short*)carve(2 * 16384 * 2);
    float* b1 = (float*)carve(512);
    float* b2 = (float*)carve(512);
    uint32_t* off_c = (uint32_t*)carve((size_t)NP * 4);
    uint32_t* off_a = (uint32_t*)carve((size_t)NP * 4);
    uint32_t* off_h = (uint32_t*)carve((size_t)NA * 4);
    int* colAll = (int*)carve(((size_t)Etot + 384 * (size_t)totB) * 4);
    uint2* pairs = (uint2*)carve((size_t)Etot * 8);
    int* gboff = (int*)carve((size_t)(totB + 1) * 4);
    int* bcur  = (int*)carve((size_t)totB * 4);
    int* bcnt  = (int*)carve((size_t)totB * 4);
    if (cur > ws_size) return;

    const int EcPad = Ec + 384 * nbc;
    const int EaPad = Ea + 384 * nba;
    int* col_c = colAll;
    int* col_a = colAll + EcPad;
    int* col_h = colAll + EcPad + EaPad;

    // ---- prologue: memset + {cvt, prep, hist, zero-rows} in one dispatch ----
    hipMemsetAsync(bcnt, 0, (size_t)totB * 4, stream);
    const int nbCvt = ((NP + NA) * 16 + 255) / 256;
    const int nbHist = (Etot + 16383) / 16384;
    prologue_kernel<<<nbCvt + 192 + nbHist + 1, 256, 0, stream>>>(
        x_p, x_a, xb_p, xb_a, NP, NA, nbCvt,
        l1c_Wl, l1c_bl, l1c_Wr, l1a_Wl, l1a_bl, l1a_Wr,
        l2c_Wl, l2c_bl, l2c_Wr, l2a_Wl, l2a_bl, l2a_Wr,
        l1h_Wl, l1h_Wr, W1hi, W1lo, b1, W2hi, W2lo, b2, WHhi, WHlo,
        c_dst, Ec, a_dst, Ea, h_dst, Eh, nbc, nba, totB, bcnt, nbHist, S1, SH);

    // ---- CSR build (padded, packed off|deg) ----
    bucket_scan_kernel<<<3, 256, 0, stream>>>(bcnt, nbc, nba, nbh, Ec, Ea, Eh,
                                              gboff, bcur);
    partition_kernel<<<(Etot + 2047) / 2048, 256, 0, stream>>>(
        c_src, c_dst, Ec, a_src, a_dst, Ea, h_src, h_dst, Eh,
        nbc, nba, totB, bcur, pairs);
    bucket_build_kernel<<<totB, 256, 0, stream>>>(
        pairs, gboff, nbc, nba, NP, NA, Ec, Ea,
        off_c, off_a, off_h, col_c, col_a, col_h);

    // ---- layer 1 ----
    const int rows_l1 = 2 * NP + NA;
    agg_l1_kernel<<<(rows_l1 + 3) / 4, 256, 0, stream>>>(
        xb_p, xb_a, off_c, col_c, off_a, col_a, off_h, col_h, S1, S2, SH, NP, NA);
    const int nbP = (NP + 127) / 128;
    const int nbA = (NA + 127) / 128;
    transform_l1_kernel<<<nbP + nbA, 256, 0, stream>>>(
        (const unsigned short*)S1, (const unsigned short*)S2,
        (const unsigned short*)xb_p, W1hi, W1lo, b1,
        (const unsigned short*)SH, (const unsigned short*)xb_a, WHhi, WHlo, l1h_bl,
        (unsigned short*)S1, (unsigned short*)SH, NP, NA, nbP);

    // ---- layer 2 (head fused into transform) ----
    agg_l2_kernel<<<(2 * NP + 3) / 4, 256, 0, stream>>>(
        S1, SH, off_c, col_c, off_a, col_a, S2, S3, NP);
    transform_p2_head_kernel<<<nbP, 256, 0, stream>>>(
        (const unsigned short*)S2, (const unsigned short*)S3,
        (const unsigned short*)S1, W2hi, W2lo, b2,
        linW, linb, (float*)d_out, NP);
}

// Round 13
// 257.855 us; speedup vs baseline: 1.2224x; 1.0731x over previous
//
#include <hip/hip_runtime.h>
#include <hip/hip_bf16.h>
#include <cstdint>

// ---------------------------------------------------------------------------
// FullHeteroGCN: 2-layer hetero GraphSAGE (mean aggr).
// R13: aggs are AT the device BW floor (74us = 6.2 TB/s logical gather;
// == m13's 6.29 TB/s ceiling) — leave them. Cuts elsewhere:
//  - single RNE-bf16 weights (drop hi/lo split): halves transform MFMA +
//    LDS staging; error budget: +~2e-3/layer, absmax ~0.010-0.016 < 0.0247.
//  - transforms at 3 blocks/CU (32KB W tile, launch_bounds(256,3)).
//  - partition pairs packed uint32 (src<<7|dst&127): halves pairs traffic.
// Head fused into p2 transform (R12). Padded CSR (zero-row pads, off|deg
// packed). Activations bf16 (cvt_pk RNE); f32 accumulation.
// ---------------------------------------------------------------------------

typedef __attribute__((ext_vector_type(8))) short bf16x8;
typedef __attribute__((ext_vector_type(4))) float f32x4;

#define HB 2048          // max total buckets (LDS arrays); totB = 1564 here
#define BCAP 6144        // bucket_build col staging capacity (padded edges)

__device__ __forceinline__ void gload_lds16(const void* g, void* l) {
    __builtin_amdgcn_global_load_lds(
        (const __attribute__((address_space(1))) unsigned int*)g,
        (__attribute__((address_space(3))) unsigned int*)l,
        16, 0, 0);
}
__device__ __forceinline__ f32x4 mfma16(bf16x8 a, bf16x8 b, f32x4 c) {
    return __builtin_amdgcn_mfma_f32_16x16x32_bf16(a, b, c, 0, 0, 0);
}
// packed f32->bf16 RNE, one instruction
__device__ __forceinline__ uint32_t cvtpk(float lo, float hi) {
    uint32_t r;
    asm("v_cvt_pk_bf16_f32 %0, %1, %2" : "=v"(r) : "v"(lo), "v"(hi));
    return r;
}
__device__ __forceinline__ unsigned short bf16_1(float v) {
    uint32_t r;
    asm("v_cvt_pk_bf16_f32 %0, %1, %2" : "=v"(r) : "v"(v), "v"(v));
    return (unsigned short)r;
}
__device__ __forceinline__ float blo(uint32_t v) { return __uint_as_float(v << 16); }
__device__ __forceinline__ float bhi(uint32_t v) { return __uint_as_float(v & 0xFFFF0000u); }

// ======================= CSR build (bucket partition) =======================

__global__ __launch_bounds__(256)
void bucket_scan_kernel(const int* __restrict__ bcnt, int nbc, int nba, int nbh,
                        int Ec, int Ea, int Eh,
                        int* __restrict__ gboff, int* __restrict__ bcur) {
    const int r  = blockIdx.x;
    const int sb = (r == 0) ? 0 : (r == 1) ? nbc : nbc + nba;
    const int nb = (r == 0) ? nbc : (r == 1) ? nba : nbh;
    const int base = (r == 0) ? 0 : (r == 1) ? Ec : Ec + Ea;
    const int tid = threadIdx.x;
    __shared__ int sm[256];
    __shared__ int carry;
    if (tid == 0) carry = base;
    __syncthreads();
    for (int c0 = 0; c0 < nb; c0 += 256) {
        int i = c0 + tid;
        int v = (i < nb) ? bcnt[sb + i] : 0;
        sm[tid] = v; __syncthreads();
        for (int d = 1; d < 256; d <<= 1) {
            int t = (tid >= d) ? sm[tid - d] : 0;
            __syncthreads();
            sm[tid] += t;
            __syncthreads();
        }
        int pre = carry + sm[tid] - v;
        if (i < nb) { gboff[sb + i] = pre; bcur[sb + i] = pre; }
        int tot = sm[255];
        __syncthreads();
        if (tid == 0) carry += tot;
        __syncthreads();
    }
    if (tid == 0 && r == 2) gboff[nbc + nba + nbh] = Ec + Ea + Eh;
}

// pairs packed: (src << 7) | (dst & 127)  [src < 2^17, bucket-local dst 7b]
__global__ __launch_bounds__(256)
void partition_kernel(const int* __restrict__ sc, const int* __restrict__ dc, int Ec,
                      const int* __restrict__ sa, const int* __restrict__ da, int Ea,
                      const int* __restrict__ sh, const int* __restrict__ dh, int Eh,
                      int nbc, int nba, int totB,
                      int* __restrict__ bcur, uint32_t* __restrict__ pairs) {
    __shared__ int lbin[HB];
    __shared__ int gbase[HB];
    __shared__ int swork[256];
    __shared__ uint32_t sorted[2048];
    __shared__ unsigned short sbin[2048];
    const int tid = threadIdx.x;
    const int Etot = Ec + Ea + Eh;
    const int start = blockIdx.x * 2048;
    const int cnt = min(2048, Etot - start);
    for (int b = tid; b < HB; b += 256) lbin[b] = 0;
    __syncthreads();
    uint32_t esrc[8], edst[8]; int ebin[8];
#pragma unroll
    for (int k = 0; k < 8; ++k) {
        int i = start + k * 256 + tid;
        int bin = -1; uint32_t s = 0, d = 0;
        if (i < Etot) {
            if (i < Ec)           { s = sc[i];           d = dc[i];           bin = (int)(d >> 7); }
            else if (i < Ec + Ea) { s = sa[i - Ec];      d = da[i - Ec];      bin = nbc + (int)(d >> 7); }
            else                  { s = sh[i - Ec - Ea]; d = dh[i - Ec - Ea]; bin = nbc + nba + (int)(d >> 7); }
            atomicAdd(&lbin[bin], 1);
        }
        esrc[k] = s; edst[k] = d; ebin[k] = bin;
    }
    __syncthreads();
    const int base8 = tid * 8;
    int lv[8]; int s0 = 0;
#pragma unroll
    for (int j = 0; j < 8; ++j) { lv[j] = lbin[base8 + j]; s0 += lv[j]; }
    swork[tid] = s0; __syncthreads();
    for (int d = 1; d < 256; d <<= 1) {
        int t = (tid >= d) ? swork[tid - d] : 0;
        __syncthreads();
        swork[tid] += t;
        __syncthreads();
    }
    int run = swork[tid] - s0;
    __syncthreads();
#pragma unroll
    for (int j = 0; j < 8; ++j) { lbin[base8 + j] = run; run += lv[j]; }
    __syncthreads();
    for (int b = tid; b < totB; b += 256) {
        int off = lbin[b];
        int c = lbin[b + 1] - off;
        if (c > 0) gbase[b] = atomicAdd(&bcur[b], c) - off;
    }
    __syncthreads();
#pragma unroll
    for (int k = 0; k < 8; ++k) {
        if (ebin[k] >= 0) {
            int p = atomicAdd(&lbin[ebin[k]], 1);
            sorted[p] = (esrc[k] << 7) | (edst[k] & 127u);
            sbin[p] = (unsigned short)ebin[k];
        }
    }
    __syncthreads();
    for (int p = tid; p < cnt; p += 256)
        pairs[gbase[sbin[p]] + p] = sorted[p];
}

// One block per bucket (<=128 dsts): LDS count -> padded scan -> packed
// off|deg write; colbuf pre-filled with zero-row index; scatter; coalesced
// col write. Padded layout: bucket base = (e0-relbase) + 384*lb.
__global__ __launch_bounds__(256)
void bucket_build_kernel(const uint32_t* __restrict__ pairs,
                         const int* __restrict__ gboff,
                         int nbc, int nba,
                         int NP, int NA, int Ec, int Ea,
                         uint32_t* __restrict__ off_c, uint32_t* __restrict__ off_a,
                         uint32_t* __restrict__ off_h,
                         int* __restrict__ col_c, int* __restrict__ col_a,
                         int* __restrict__ col_h) {
    const int bin = blockIdx.x;
    int lb, relbase, n, zrow; uint32_t* off; int* colp;
    if (bin < nbc)            { lb = bin;             relbase = 0;       n = NP; zrow = NP; off = off_c; colp = col_c; }
    else if (bin < nbc + nba) { lb = bin - nbc;       relbase = Ec;      n = NP; zrow = NA; off = off_a; colp = col_a; }
    else                      { lb = bin - nbc - nba; relbase = Ec + Ea; n = NA; zrow = NP; off = off_h; colp = col_h; }
    const int d0 = lb << 7;
    const int e0 = gboff[bin], e1 = gboff[bin + 1];
    const int padBase = (e0 - relbase) + lb * 384;
    const int tid = threadIdx.x;
    __shared__ int lcnt[128];
    __shared__ int lcur[128];
    __shared__ int colbuf[BCAP];
    if (tid < 128) lcnt[tid] = 0;
    __syncthreads();
    for (int e = e0 + tid; e < e1; e += 256)
        atomicAdd(&lcnt[pairs[e] & 127u], 1);
    __syncthreads();
    int c = 0, pc = 0;
    if (tid < 128) { c = lcnt[tid]; pc = (c + 3) & ~3; lcnt[tid] = pc; }
    __syncthreads();
    for (int d = 1; d < 128; d <<= 1) {
        int t = (tid < 128 && tid >= d) ? lcnt[tid - d] : 0;
        __syncthreads();
        if (tid < 128) lcnt[tid] += t;
        __syncthreads();
    }
    if (tid < 128) {
        int excl = lcnt[tid] - pc;
        lcur[tid] = excl;
        int d = d0 + tid;
        if (d < n) off[d] = (uint32_t)(padBase + excl) | ((uint32_t)c << 22);
    }
    __syncthreads();
    const int cntPad = lcnt[127];
    if (cntPad <= BCAP) {
        for (int i = tid; i < cntPad; i += 256) colbuf[i] = zrow;
        __syncthreads();
        for (int e = e0 + tid; e < e1; e += 256) {
            uint32_t pr = pairs[e];
            int p = atomicAdd(&lcur[pr & 127u], 1);
            colbuf[p] = (int)(pr >> 7);
        }
        __syncthreads();
        for (int i = tid; i < cntPad; i += 256) colp[padBase + i] = colbuf[i];
    } else {  // overflow fallback
        for (int i = tid; i < cntPad; i += 256) colp[padBase + i] = zrow;
        __syncthreads();
        for (int e = e0 + tid; e < e1; e += 256) {
            uint32_t pr = pairs[e];
            int p = atomicAdd(&lcur[pr & 127u], 1);
            colp[padBase + p] = (int)(pr >> 7);
        }
    }
}

// ======================= prologue (cvt + prep + hist + zero rows) ==========

__global__ __launch_bounds__(256)
void prologue_kernel(const float* __restrict__ x_p, const float* __restrict__ x_a,
                     uint32_t* __restrict__ xb_p, uint32_t* __restrict__ xb_a,
                     int NP, int NA, int nbCvt,
                     const float* l1cWl, const float* l1cbl, const float* l1cWr,
                     const float* l1aWl, const float* l1abl, const float* l1aWr,
                     const float* l2cWl, const float* l2cbl, const float* l2cWr,
                     const float* l2aWl, const float* l2abl, const float* l2aWr,
                     const float* lhWl, const float* lhWr,
                     unsigned short* W1, float* b1,
                     unsigned short* W2, float* b2,
                     unsigned short* WH,
                     const int* __restrict__ dc, int Ec,
                     const int* __restrict__ da, int Ea,
                     const int* __restrict__ dh, int Eh,
                     int nbc, int nba, int totB, int* __restrict__ bcnt,
                     int nbHist, uint32_t* __restrict__ S1, uint32_t* __restrict__ SH) {
    __shared__ int lh[HB];
    const int b = blockIdx.x, tid = threadIdx.x;
    if (b < nbCvt) {
        int i = b * 256 + tid;
        const float* X; uint32_t* Y; int j;
        const int n80 = NP * 16;
        if (i < n80)                 { X = x_p; Y = xb_p; j = i; }
        else if (i < n80 + NA * 16)  { X = x_a; Y = xb_a; j = i - n80; }
        else return;
        float4 v0 = *(const float4*)(X + (size_t)j * 8);
        float4 v1 = *(const float4*)(X + (size_t)j * 8 + 4);
        uint4 o;
        o.x = cvtpk(v0.x, v0.y); o.y = cvtpk(v0.z, v0.w);
        o.z = cvtpk(v1.x, v1.y); o.w = cvtpk(v1.z, v1.w);
        *(uint4*)(Y + (size_t)j * 4) = o;
    } else if (b < nbCvt + 192) {
        const int bid = b - nbCvt;
        if (bid < 64) {
            int i = bid * 256 + tid;
            W1[i]         = bf16_1(0.5f * l1cWl[i]);
            W1[16384 + i] = bf16_1(0.5f * l1aWl[i]);
            W1[32768 + i] = bf16_1(0.5f * (l1cWr[i] + l1aWr[i]));
            if (i < 128) b1[i] = 0.5f * (l1cbl[i] + l1abl[i]);
        } else if (bid < 128) {
            int i = (bid - 64) * 256 + tid;
            W2[i]         = bf16_1(0.5f * l2cWl[i]);
            W2[16384 + i] = bf16_1(0.5f * l2aWl[i]);
            W2[32768 + i] = bf16_1(0.5f * (l2cWr[i] + l2aWr[i]));
            if (i < 128) b2[i] = 0.5f * (l2cbl[i] + l2abl[i]);
        } else {
            int i = (bid - 128) * 256 + tid;
            WH[i]         = bf16_1(lhWl[i]);
            WH[16384 + i] = bf16_1(lhWr[i]);
        }
    } else if (b < nbCvt + 192 + nbHist) {
        // bucket histogram via LDS
        const int hb = b - nbCvt - 192;
        for (int k = tid; k < HB; k += 256) lh[k] = 0;
        __syncthreads();
        const int Etot = Ec + Ea + Eh;
        const int start = hb * 16384;
        const int end = min(start + 16384, Etot);
        for (int i = start + tid; i < end; i += 256) {
            int bin;
            if (i < Ec)            bin = dc[i] >> 7;
            else if (i < Ec + Ea)  bin = nbc + (da[i - Ec] >> 7);
            else                   bin = nbc + nba + (dh[i - Ec - Ea] >> 7);
            atomicAdd(&lh[bin], 1);
        }
        __syncthreads();
        for (int k = tid; k < totB; k += 256) {
            int v = lh[k];
            if (v) atomicAdd(&bcnt[k], v);
        }
    } else {
        // zero rows at index N of each gathered table
        const int w = tid & 63, which = tid >> 6;
        uint32_t* dst = (which == 0) ? xb_p + (size_t)NP * 64
                      : (which == 1) ? xb_a + (size_t)NA * 64
                      : (which == 2) ? S1 + (size_t)NP * 64
                                     : SH + (size_t)NA * 64;
        dst[w] = 0;
    }
}

// ======================= aggregation =======================

__device__ __forceinline__ void acc8(float* a, uint4 q) {
    a[0] += blo(q.x); a[1] += bhi(q.x);
    a[2] += blo(q.y); a[3] += bhi(q.y);
    a[4] += blo(q.z); a[5] += bhi(q.z);
    a[6] += blo(q.w); a[7] += bhi(q.w);
}

// padded quad-edge gather mean: 1 wave/row; uniform quad count (no
// predication); 32-bit byte-offset gathers; cvt_pk epilogue.
__device__ __forceinline__ void agg_row(const uint32_t* __restrict__ X,
                                        const uint32_t* __restrict__ offp,
                                        const int* __restrict__ col,
                                        uint32_t* __restrict__ Y, int row) {
    const int lane = threadIdx.x & 63;
    const int g = lane >> 4, t = lane & 15;
    const uint32_t pk = offp[row];
    int e = (int)(pk & 0x3FFFFFu);
    const int deg = (int)(pk >> 22);
    int nq = (deg + 3) >> 2;
    const char* Xc = (const char*)X;
    const uint32_t bo = (uint32_t)(t << 4);
    float A0[8] = {0.f, 0.f, 0.f, 0.f, 0.f, 0.f, 0.f, 0.f};
    float A1[8] = {0.f, 0.f, 0.f, 0.f, 0.f, 0.f, 0.f, 0.f};
    while (nq >= 2) {
        int sA = col[e + g];
        int sB = col[e + 4 + g];
        uint4 qA = *(const uint4*)(Xc + (((uint32_t)sA << 8) + bo));
        uint4 qB = *(const uint4*)(Xc + (((uint32_t)sB << 8) + bo));
        acc8(A0, qA); acc8(A1, qB);
        e += 8; nq -= 2;
    }
    if (nq) {
        int sA = col[e + g];
        uint4 qA = *(const uint4*)(Xc + (((uint32_t)sA << 8) + bo));
        acc8(A0, qA);
    }
    const float inv = 1.0f / (float)(deg > 0 ? deg : 1);
    float a[8];
#pragma unroll
    for (int j = 0; j < 8; ++j) {
        float v = A0[j] + A1[j];
        v += __shfl_xor(v, 16, 64);
        v += __shfl_xor(v, 32, 64);
        a[j] = v * inv;
    }
    if (g == 0) {
        uint4 o;
        o.x = cvtpk(a[0], a[1]); o.y = cvtpk(a[2], a[3]);
        o.z = cvtpk(a[4], a[5]); o.w = cvtpk(a[6], a[7]);
        *(uint4*)(Y + (size_t)row * 64 + (t << 2)) = o;
    }
}

__global__ __launch_bounds__(256)
void agg_l1_kernel(const uint32_t* __restrict__ xb_p, const uint32_t* __restrict__ xb_a,
                   const uint32_t* __restrict__ off_c, const int* __restrict__ col_c,
                   const uint32_t* __restrict__ off_a, const int* __restrict__ col_a,
                   const uint32_t* __restrict__ off_h, const int* __restrict__ col_h,
                   uint32_t* __restrict__ S1, uint32_t* __restrict__ S2,
                   uint32_t* __restrict__ SH, int NP, int NA) {
    int gw = (blockIdx.x * 256 + threadIdx.x) >> 6;
    if (gw < NP)               agg_row(xb_p, off_c, col_c, S1, gw);
    else if (gw < 2 * NP)      agg_row(xb_a, off_a, col_a, S2, gw - NP);
    else if (gw < 2 * NP + NA) agg_row(xb_p, off_h, col_h, SH, gw - 2 * NP);
}

__global__ __launch_bounds__(256)
void agg_l2_kernel(const uint32_t* __restrict__ P1, const uint32_t* __restrict__ A1,
                   const uint32_t* __restrict__ off_c, const int* __restrict__ col_c,
                   const uint32_t* __restrict__ off_a, const int* __restrict__ col_a,
                   uint32_t* __restrict__ S2, uint32_t* __restrict__ S3, int NP) {
    int gw = (blockIdx.x * 256 + threadIdx.x) >> 6;
    if (gw < NP)          agg_row(P1, off_c, col_c, S2, gw);
    else if (gw < 2 * NP) agg_row(A1, off_a, col_a, S3, gw - NP);
}

// ======================= transform (bf16 MFMA, single-W) =======================

template <int PAIRS>
__device__ __forceinline__ void transform_body(
        int blk, const unsigned short* A0, const unsigned short* A1,
        const unsigned short* A2,
        const unsigned short* __restrict__ W,
        const float* __restrict__ bias, unsigned short* Y, int N,
        unsigned short* Bs) {
    const int tid  = threadIdx.x;
    const int l    = tid & 63;
    const int wv   = tid >> 6;
    const int lrow = l & 15;
    const int lkg  = l >> 4;
    const int rw   = blk * 128 + wv * 32;

    f32x4 acc0[8], acc1[8];
#pragma unroll
    for (int t = 0; t < 8; ++t) {
        acc0[t] = (f32x4){0.f, 0.f, 0.f, 0.f};
        acc1[t] = (f32x4){0.f, 0.f, 0.f, 0.f};
    }

    int arow0 = rw + lrow;      if (arow0 >= N) arow0 = N - 1;
    int arow1 = rw + 16 + lrow; if (arow1 >= N) arow1 = N - 1;
    const int kbase = lkg << 3;
    const int cb    = lkg << 4;

#pragma unroll 1
    for (int p = 0; p < PAIRS; ++p) {
        {
            const char* src = (const char*)(W + (p << 14));
#pragma unroll
            for (int it = 0; it < 8; ++it) {
                const int L = it * 4096 + tid * 16;
                const int j = L >> 8;
                const int g = (j << 8) + ((L & 255) ^ ((j & 7) << 4));
                gload_lds16(src + g, (char*)Bs + L);
            }
        }
        __syncthreads();
        const unsigned short* A = (p == 0) ? A0 : (p == 1) ? A1 : A2;
#pragma unroll
        for (int kc = 0; kc < 4; ++kc) {
            bf16x8 a0 = *(const bf16x8*)(A + (size_t)arow0 * 128 + kc * 32 + kbase);
            bf16x8 a1 = *(const bf16x8*)(A + (size_t)arow1 * 128 + kc * 32 + kbase);
            const int cbk = kc * 64 + cb;
#pragma unroll
            for (int t = 0; t < 8; ++t) {
                const int jt   = (t << 4) + lrow;
                const int addr = (jt << 8) + (cbk ^ ((jt & 7) << 4));
                bf16x8 bh = *(const bf16x8*)((const char*)Bs + addr);
                acc0[t] = mfma16(a0, bh, acc0[t]);
                acc1[t] = mfma16(a1, bh, acc1[t]);
            }
        }
        __syncthreads();
    }
#pragma unroll
    for (int t = 0; t < 8; ++t) {
        const int c = t * 16 + lrow;
        const float bv = bias[c];
#pragma unroll
        for (int r = 0; r < 4; ++r) {
            int row0 = rw + (lkg << 2) + r;
            if (row0 < N)
                Y[(size_t)row0 * 128 + c] = bf16_1(fmaxf(acc0[t][r] + bv, 0.f));
            int row1 = row0 + 16;
            if (row1 < N)
                Y[(size_t)row1 * 128 + c] = bf16_1(fmaxf(acc1[t][r] + bv, 0.f));
        }
    }
}

__global__ __launch_bounds__(256, 3)
void transform_l1_kernel(const unsigned short* S1, const unsigned short* S2,
                         const unsigned short* xb_p,
                         const unsigned short* __restrict__ W1,
                         const float* __restrict__ b1,
                         const unsigned short* SH, const unsigned short* xb_a,
                         const unsigned short* __restrict__ WH,
                         const float* __restrict__ bh,
                         unsigned short* P1out, unsigned short* A1out,
                         int NP, int NA, int nbP) {
    __shared__ unsigned short Bs[128 * 128];   // 32 KB
    if ((int)blockIdx.x < nbP)
        transform_body<3>(blockIdx.x, S1, S2, xb_p, W1, b1, P1out, NP, Bs);
    else
        transform_body<2>(blockIdx.x - nbP, SH, xb_a, nullptr, WH, bh,
                          A1out, NA, Bs);
}

// transform_p2 with FUSED classifier head: p2 = relu(sum_p A_p@W_p^T + b)
// stays in registers; out[row][cls] = p2[row,:] . linW[cls,:] + linb[cls]
// via LDS-staged linW and a 16-lane shfl_xor reduce. No p2 store.
__global__ __launch_bounds__(256, 3)
void transform_p2_head_kernel(const unsigned short* A0, const unsigned short* A1,
                              const unsigned short* A2,
                              const unsigned short* __restrict__ W,
                              const float* __restrict__ bias,
                              const float* __restrict__ linW,
                              const float* __restrict__ linb,
                              float* __restrict__ out, int N) {
    __shared__ unsigned short Bs[128 * 128];   // 32 KB
    __shared__ float lwd[1024];   // linW [8][128]
    __shared__ float lbd[8];
    const int tid  = threadIdx.x;
    const int l    = tid & 63;
    const int wv   = tid >> 6;
    const int lrow = l & 15;
    const int lkg  = l >> 4;
    const int rw   = (int)blockIdx.x * 128 + wv * 32;

    for (int i = tid; i < 1024; i += 256) lwd[i] = linW[i];
    if (tid < 8) lbd[tid] = linb[tid];

    f32x4 acc0[8], acc1[8];
#pragma unroll
    for (int t = 0; t < 8; ++t) {
        acc0[t] = (f32x4){0.f, 0.f, 0.f, 0.f};
        acc1[t] = (f32x4){0.f, 0.f, 0.f, 0.f};
    }

    int arow0 = rw + lrow;      if (arow0 >= N) arow0 = N - 1;
    int arow1 = rw + 16 + lrow; if (arow1 >= N) arow1 = N - 1;
    const int kbase = lkg << 3;
    const int cb    = lkg << 4;

#pragma unroll 1
    for (int p = 0; p < 3; ++p) {
        {
            const char* src = (const char*)(W + (p << 14));
#pragma unroll
            for (int it = 0; it < 8; ++it) {
                const int L = it * 4096 + tid * 16;
                const int j = L >> 8;
                const int g = (j << 8) + ((L & 255) ^ ((j & 7) << 4));
                gload_lds16(src + g, (char*)Bs + L);
            }
        }
        __syncthreads();
        const unsigned short* A = (p == 0) ? A0 : (p == 1) ? A1 : A2;
#pragma unroll
        for (int kc = 0; kc < 4; ++kc) {
            bf16x8 a0 = *(const bf16x8*)(A + (size_t)arow0 * 128 + kc * 32 + kbase);
            bf16x8 a1 = *(const bf16x8*)(A + (size_t)arow1 * 128 + kc * 32 + kbase);
            const int cbk = kc * 64 + cb;
#pragma unroll
            for (int t = 0; t < 8; ++t) {
                const int jt   = (t << 4) + lrow;
                const int addr = (jt << 8) + (cbk ^ ((jt & 7) << 4));
                bf16x8 bh = *(const bf16x8*)((const char*)Bs + addr);
                acc0[t] = mfma16(a0, bh, acc0[t]);
                acc1[t] = mfma16(a1, bh, acc1[t]);
            }
        }
        __syncthreads();
    }
    // bias + relu in-register -> p2
#pragma unroll
    for (int t = 0; t < 8; ++t) {
        const float bv = bias[t * 16 + lrow];
#pragma unroll
        for (int r = 0; r < 4; ++r) {
            acc0[t][r] = fmaxf(acc0[t][r] + bv, 0.f);
            acc1[t][r] = fmaxf(acc1[t][r] + bv, 0.f);
        }
    }
    // head: per class, dot owned cols then reduce across the 16-lane group
    float o0[4], o1[4];
#pragma unroll
    for (int cls = 0; cls < 8; ++cls) {
        float wvv[8];
#pragma unroll
        for (int t = 0; t < 8; ++t) wvv[t] = lwd[cls * 128 + t * 16 + lrow];
#pragma unroll
        for (int r = 0; r < 4; ++r) {
            float s0 = 0.f, s1 = 0.f;
#pragma unroll
            for (int t = 0; t < 8; ++t) {
                s0 += acc0[t][r] * wvv[t];
                s1 += acc1[t][r] * wvv[t];
            }
            s0 += __shfl_xor(s0, 1, 64); s0 += __shfl_xor(s0, 2, 64);
            s0 += __shfl_xor(s0, 4, 64); s0 += __shfl_xor(s0, 8, 64);
            s1 += __shfl_xor(s1, 1, 64); s1 += __shfl_xor(s1, 2, 64);
            s1 += __shfl_xor(s1, 4, 64); s1 += __shfl_xor(s1, 8, 64);
            if (lrow == cls) { o0[r] = s0; o1[r] = s1; }
        }
    }
    if (lrow < 8) {
        const float lbv = lbd[lrow];
#pragma unroll
        for (int r = 0; r < 4; ++r) {
            int row0 = rw + (lkg << 2) + r;
            if (row0 < N) out[(size_t)row0 * 8 + lrow] = o0[r] + lbv;
            int row1 = row0 + 16;
            if (row1 < N) out[(size_t)row1 * 8 + lrow] = o1[r] + lbv;
        }
    }
}

extern "C" void kernel_launch(void* const* d_in, const int* in_sizes, int n_in,
                              void* d_out, int out_size, void* d_ws, size_t ws_size,
                              hipStream_t stream) {
    const float* x_p = (const float*)d_in[0];
    const float* x_a = (const float*)d_in[1];
    const int* c_src = (const int*)d_in[2];
    const int* c_dst = (const int*)d_in[3];
    const int* a_src = (const int*)d_in[4];
    const int* a_dst = (const int*)d_in[5];
    const int* h_src = (const int*)d_in[6];
    const int* h_dst = (const int*)d_in[7];
    const float* l1c_Wl = (const float*)d_in[8];
    const float* l1c_bl = (const float*)d_in[9];
    const float* l1c_Wr = (const float*)d_in[10];
    const float* l1a_Wl = (const float*)d_in[11];
    const float* l1a_bl = (const float*)d_in[12];
    const float* l1a_Wr = (const float*)d_in[13];
    const float* l1h_Wl = (const float*)d_in[14];
    const float* l1h_bl = (const float*)d_in[15];
    const float* l1h_Wr = (const float*)d_in[16];
    const float* l2c_Wl = (const float*)d_in[17];
    const float* l2c_bl = (const float*)d_in[18];
    const float* l2c_Wr = (const float*)d_in[19];
    const float* l2a_Wl = (const float*)d_in[20];
    const float* l2a_bl = (const float*)d_in[21];
    const float* l2a_Wr = (const float*)d_in[22];
    const float* linW   = (const float*)d_in[26];
    const float* linb   = (const float*)d_in[27];

    const int NP = in_sizes[0] / 128;
    const int NA = in_sizes[1] / 128;
    const int Ec = in_sizes[2];
    const int Ea = in_sizes[4];
    const int Eh = in_sizes[6];
    const int Etot = Ec + Ea + Eh;

    const int nbc = (NP + 127) >> 7;
    const int nba = (NP + 127) >> 7;
    const int nbh = (NA + 127) >> 7;
    const int totB = nbc + nba + nbh;
    if (totB > HB) return;

    // ---- carve workspace ----
    char* base = (char*)d_ws;
    size_t cur = 0;
    auto carve = [&](size_t bytes) -> char* {
        char* p = base + cur;
        cur = (cur + bytes + 255) & ~(size_t)255;
        return p;
    };
    uint32_t* xb_p = (uint32_t*)carve((size_t)(NP + 1) * 128 * 2);  // +zero row
    uint32_t* xb_a = (uint32_t*)carve((size_t)(NA + 1) * 128 * 2);  // +zero row
    uint32_t* S1 = (uint32_t*)carve((size_t)(NP + 1) * 128 * 2);    // +zero row
    uint32_t* S2 = (uint32_t*)carve((size_t)NP * 128 * 2);
    uint32_t* S3 = (uint32_t*)carve((size_t)NP * 128 * 2);
    uint32_t* SH = (uint32_t*)carve((size_t)(NA + 1) * 128 * 2);    // +zero row
    unsigned short* W1 = (unsigned short*)carve(3 * 16384 * 2);
    unsigned short* W2 = (unsigned short*)carve(3 * 16384 * 2);
    unsigned short* WH = (unsigned short*)carve(2 * 16384 * 2);
    float* b1 = (float*)carve(512);
    float* b2 = (float*)carve(512);
    uint32_t* off_c = (uint32_t*)carve((size_t)NP * 4);
    uint32_t* off_a = (uint32_t*)carve((size_t)NP * 4);
    uint32_t* off_h = (uint32_t*)carve((size_t)NA * 4);
    int* colAll = (int*)carve(((size_t)Etot + 384 * (size_t)totB) * 4);
    uint32_t* pairs = (uint32_t*)carve((size_t)Etot * 4);
    int* gboff = (int*)carve((size_t)(totB + 1) * 4);
    int* bcur  = (int*)carve((size_t)totB * 4);
    int* bcnt  = (int*)carve((size_t)totB * 4);
    if (cur > ws_size) return;

    const int EcPad = Ec + 384 * nbc;
    const int EaPad = Ea + 384 * nba;
    int* col_c = colAll;
    int* col_a = colAll + EcPad;
    int* col_h = colAll + EcPad + EaPad;

    // ---- prologue: memset + {cvt, prep, hist, zero-rows} in one dispatch ----
    hipMemsetAsync(bcnt, 0, (size_t)totB * 4, stream);
    const int nbCvt = ((NP + NA) * 16 + 255) / 256;
    const int nbHist = (Etot + 16383) / 16384;
    prologue_kernel<<<nbCvt + 192 + nbHist + 1, 256, 0, stream>>>(
        x_p, x_a, xb_p, xb_a, NP, NA, nbCvt,
        l1c_Wl, l1c_bl, l1c_Wr, l1a_Wl, l1a_bl, l1a_Wr,
        l2c_Wl, l2c_bl, l2c_Wr, l2a_Wl, l2a_bl, l2a_Wr,
        l1h_Wl, l1h_Wr, W1, b1, W2, b2, WH,
        c_dst, Ec, a_dst, Ea, h_dst, Eh, nbc, nba, totB, bcnt, nbHist, S1, SH);

    // ---- CSR build (padded, packed off|deg, packed uint32 pairs) ----
    bucket_scan_kernel<<<3, 256, 0, stream>>>(bcnt, nbc, nba, nbh, Ec, Ea, Eh,
                                              gboff, bcur);
    partition_kernel<<<(Etot + 2047) / 2048, 256, 0, stream>>>(
        c_src, c_dst, Ec, a_src, a_dst, Ea, h_src, h_dst, Eh,
        nbc, nba, totB, bcur, pairs);
    bucket_build_kernel<<<totB, 256, 0, stream>>>(
        pairs, gboff, nbc, nba, NP, NA, Ec, Ea,
        off_c, off_a, off_h, col_c, col_a, col_h);

    // ---- layer 1 ----
    const int rows_l1 = 2 * NP + NA;
    agg_l1_kernel<<<(rows_l1 + 3) / 4, 256, 0, stream>>>(
        xb_p, xb_a, off_c, col_c, off_a, col_a, off_h, col_h, S1, S2, SH, NP, NA);
    const int nbP = (NP + 127) / 128;
    const int nbA = (NA + 127) / 128;
    transform_l1_kernel<<<nbP + nbA, 256, 0, stream>>>(
        (const unsigned short*)S1, (const unsigned short*)S2,
        (const unsigned short*)xb_p, W1, b1,
        (const unsigned short*)SH, (const unsigned short*)xb_a, WH, l1h_bl,
        (unsigned short*)S1, (unsigned short*)SH, NP, NA, nbP);

    // ---- layer 2 (head fused into transform) ----
    agg_l2_kernel<<<(2 * NP + 3) / 4, 256, 0, stream>>>(
        S1, SH, off_c, col_c, off_a, col_a, S2, S3, NP);
    transform_p2_head_kernel<<<nbP, 256, 0, stream>>>(
        (const unsigned short*)S2, (const unsigned short*)S3,
        (const unsigned short*)S1, W2, b2,
        linW, linb, (float*)d_out, NP);
}

// Round 14
// 254.970 us; speedup vs baseline: 1.2362x; 1.0113x over previous
//
#include <hip/hip_runtime.h>
#include <hip/hip_bf16.h>
#include <cstdint>

// ---------------------------------------------------------------------------
// FullHeteroGCN: 2-layer hetero GraphSAGE (mean aggr).
// R14: revert transforms to launch_bounds(256,2) — R13's (256,3) caps the
// allocator at ~84 VGPR but the body holds 64 acc + 16 frag + temps -> forced
// scratch spill (R1 lesson). Single-block 1024-thr bucket scan (old 3-block
// version serialized 4 chunks x 16 barriers). Aggs untouched: 74/49us =
// 6.2-6.7 TB/s combined logical traffic == device random-gather service
// ceiling (3 structurally different aggs in R8/R10/R11 all converged here).
// Single RNE-bf16 weights; padded CSR; head fused into p2; f32 accumulation.
// ---------------------------------------------------------------------------

typedef __attribute__((ext_vector_type(8))) short bf16x8;
typedef __attribute__((ext_vector_type(4))) float f32x4;

#define HB 2048          // max total buckets; totB = 1564 here
#define BCAP 6144        // bucket_build col staging capacity (padded edges)

__device__ __forceinline__ void gload_lds16(const void* g, void* l) {
    __builtin_amdgcn_global_load_lds(
        (const __attribute__((address_space(1))) unsigned int*)g,
        (__attribute__((address_space(3))) unsigned int*)l,
        16, 0, 0);
}
__device__ __forceinline__ f32x4 mfma16(bf16x8 a, bf16x8 b, f32x4 c) {
    return __builtin_amdgcn_mfma_f32_16x16x32_bf16(a, b, c, 0, 0, 0);
}
// packed f32->bf16 RNE, one instruction
__device__ __forceinline__ uint32_t cvtpk(float lo, float hi) {
    uint32_t r;
    asm("v_cvt_pk_bf16_f32 %0, %1, %2" : "=v"(r) : "v"(lo), "v"(hi));
    return r;
}
__device__ __forceinline__ unsigned short bf16_1(float v) {
    uint32_t r;
    asm("v_cvt_pk_bf16_f32 %0, %1, %2" : "=v"(r) : "v"(v), "v"(v));
    return (unsigned short)r;
}
__device__ __forceinline__ float blo(uint32_t v) { return __uint_as_float(v << 16); }
__device__ __forceinline__ float bhi(uint32_t v) { return __uint_as_float(v & 0xFFFF0000u); }

// ======================= CSR build (bucket partition) =======================

// Single block, 1024 threads: exclusive scan over all totB bucket counts,
// with per-relation base offsets folded in analytically.
__global__ __launch_bounds__(1024)
void scan_fast_kernel(const int* __restrict__ bcnt, int nbc, int nba, int nbh,
                      int Ec, int Ea, int Eh,
                      int* __restrict__ gboff, int* __restrict__ bcur) {
    __shared__ int sm[1024];
    __shared__ int ex2[HB];
    const int tid = threadIdx.x;
    const int totB = nbc + nba + nbh;
    const int j0 = tid * 2, j1 = tid * 2 + 1;
    int v0 = (j0 < totB) ? bcnt[j0] : 0;
    int v1 = (j1 < totB) ? bcnt[j1] : 0;
    int s = v0 + v1;
    sm[tid] = s;
    __syncthreads();
    for (int d = 1; d < 1024; d <<= 1) {
        int t = (tid >= d) ? sm[tid - d] : 0;
        __syncthreads();
        sm[tid] += t;
        __syncthreads();
    }
    int ep = sm[tid] - s;           // exclusive prefix of pair
    ex2[j0] = ep;
    ex2[j1] = ep + v0;
    __syncthreads();
    const int exSeg1 = ex2[nbc];
    const int exSeg2 = ex2[nbc + nba];
#pragma unroll
    for (int q = 0; q < 2; ++q) {
        int j = tid * 2 + q;
        if (j < totB) {
            int base, exSeg;
            if (j < nbc)            { base = 0;       exSeg = 0; }
            else if (j < nbc + nba) { base = Ec;      exSeg = exSeg1; }
            else                    { base = Ec + Ea; exSeg = exSeg2; }
            int val = base + ex2[j] - exSeg;
            gboff[j] = val; bcur[j] = val;
        }
    }
    if (tid == 0) gboff[totB] = Ec + Ea + Eh;
}

// pairs packed: (src << 7) | (dst & 127)  [src < 2^17, bucket-local dst 7b]
__global__ __launch_bounds__(256)
void partition_kernel(const int* __restrict__ sc, const int* __restrict__ dc, int Ec,
                      const int* __restrict__ sa, const int* __restrict__ da, int Ea,
                      const int* __restrict__ sh, const int* __restrict__ dh, int Eh,
                      int nbc, int nba, int totB,
                      int* __restrict__ bcur, uint32_t* __restrict__ pairs) {
    __shared__ int lbin[HB];
    __shared__ int gbase[HB];
    __shared__ int swork[256];
    __shared__ uint32_t sorted[2048];
    __shared__ unsigned short sbin[2048];
    const int tid = threadIdx.x;
    const int Etot = Ec + Ea + Eh;
    const int start = blockIdx.x * 2048;
    const int cnt = min(2048, Etot - start);
    for (int b = tid; b < HB; b += 256) lbin[b] = 0;
    __syncthreads();
    uint32_t esrc[8], edst[8]; int ebin[8];
#pragma unroll
    for (int k = 0; k < 8; ++k) {
        int i = start + k * 256 + tid;
        int bin = -1; uint32_t s = 0, d = 0;
        if (i < Etot) {
            if (i < Ec)           { s = sc[i];           d = dc[i];           bin = (int)(d >> 7); }
            else if (i < Ec + Ea) { s = sa[i - Ec];      d = da[i - Ec];      bin = nbc + (int)(d >> 7); }
            else                  { s = sh[i - Ec - Ea]; d = dh[i - Ec - Ea]; bin = nbc + nba + (int)(d >> 7); }
            atomicAdd(&lbin[bin], 1);
        }
        esrc[k] = s; edst[k] = d; ebin[k] = bin;
    }
    __syncthreads();
    const int base8 = tid * 8;
    int lv[8]; int s0 = 0;
#pragma unroll
    for (int j = 0; j < 8; ++j) { lv[j] = lbin[base8 + j]; s0 += lv[j]; }
    swork[tid] = s0; __syncthreads();
    for (int d = 1; d < 256; d <<= 1) {
        int t = (tid >= d) ? swork[tid - d] : 0;
        __syncthreads();
        swork[tid] += t;
        __syncthreads();
    }
    int run = swork[tid] - s0;
    __syncthreads();
#pragma unroll
    for (int j = 0; j < 8; ++j) { lbin[base8 + j] = run; run += lv[j]; }
    __syncthreads();
    for (int b = tid; b < totB; b += 256) {
        int off = lbin[b];
        int c = lbin[b + 1] - off;
        if (c > 0) gbase[b] = atomicAdd(&bcur[b], c) - off;
    }
    __syncthreads();
#pragma unroll
    for (int k = 0; k < 8; ++k) {
        if (ebin[k] >= 0) {
            int p = atomicAdd(&lbin[ebin[k]], 1);
            sorted[p] = (esrc[k] << 7) | (edst[k] & 127u);
            sbin[p] = (unsigned short)ebin[k];
        }
    }
    __syncthreads();
    for (int p = tid; p < cnt; p += 256)
        pairs[gbase[sbin[p]] + p] = sorted[p];
}

// One block per bucket (<=128 dsts): LDS count -> padded scan -> packed
// off|deg write; colbuf pre-filled with zero-row index; scatter; coalesced
// col write. Padded layout: bucket base = (e0-relbase) + 384*lb.
__global__ __launch_bounds__(256)
void bucket_build_kernel(const uint32_t* __restrict__ pairs,
                         const int* __restrict__ gboff,
                         int nbc, int nba,
                         int NP, int NA, int Ec, int Ea,
                         uint32_t* __restrict__ off_c, uint32_t* __restrict__ off_a,
                         uint32_t* __restrict__ off_h,
                         int* __restrict__ col_c, int* __restrict__ col_a,
                         int* __restrict__ col_h) {
    const int bin = blockIdx.x;
    int lb, relbase, n, zrow; uint32_t* off; int* colp;
    if (bin < nbc)            { lb = bin;             relbase = 0;       n = NP; zrow = NP; off = off_c; colp = col_c; }
    else if (bin < nbc + nba) { lb = bin - nbc;       relbase = Ec;      n = NP; zrow = NA; off = off_a; colp = col_a; }
    else                      { lb = bin - nbc - nba; relbase = Ec + Ea; n = NA; zrow = NP; off = off_h; colp = col_h; }
    const int d0 = lb << 7;
    const int e0 = gboff[bin], e1 = gboff[bin + 1];
    const int padBase = (e0 - relbase) + lb * 384;
    const int tid = threadIdx.x;
    __shared__ int lcnt[128];
    __shared__ int lcur[128];
    __shared__ int colbuf[BCAP];
    if (tid < 128) lcnt[tid] = 0;
    __syncthreads();
    for (int e = e0 + tid; e < e1; e += 256)
        atomicAdd(&lcnt[pairs[e] & 127u], 1);
    __syncthreads();
    int c = 0, pc = 0;
    if (tid < 128) { c = lcnt[tid]; pc = (c + 3) & ~3; lcnt[tid] = pc; }
    __syncthreads();
    for (int d = 1; d < 128; d <<= 1) {
        int t = (tid < 128 && tid >= d) ? lcnt[tid - d] : 0;
        __syncthreads();
        if (tid < 128) lcnt[tid] += t;
        __syncthreads();
    }
    if (tid < 128) {
        int excl = lcnt[tid] - pc;
        lcur[tid] = excl;
        int d = d0 + tid;
        if (d < n) off[d] = (uint32_t)(padBase + excl) | ((uint32_t)c << 22);
    }
    __syncthreads();
    const int cntPad = lcnt[127];
    if (cntPad <= BCAP) {
        for (int i = tid; i < cntPad; i += 256) colbuf[i] = zrow;
        __syncthreads();
        for (int e = e0 + tid; e < e1; e += 256) {
            uint32_t pr = pairs[e];
            int p = atomicAdd(&lcur[pr & 127u], 1);
            colbuf[p] = (int)(pr >> 7);
        }
        __syncthreads();
        for (int i = tid; i < cntPad; i += 256) colp[padBase + i] = colbuf[i];
    } else {  // overflow fallback
        for (int i = tid; i < cntPad; i += 256) colp[padBase + i] = zrow;
        __syncthreads();
        for (int e = e0 + tid; e < e1; e += 256) {
            uint32_t pr = pairs[e];
            int p = atomicAdd(&lcur[pr & 127u], 1);
            colp[padBase + p] = (int)(pr >> 7);
        }
    }
}

// ======================= prologue (cvt + prep + hist + zero rows) ==========

__global__ __launch_bounds__(256)
void prologue_kernel(const float* __restrict__ x_p, const float* __restrict__ x_a,
                     uint32_t* __restrict__ xb_p, uint32_t* __restrict__ xb_a,
                     int NP, int NA, int nbCvt,
                     const float* l1cWl, const float* l1cbl, const float* l1cWr,
                     const float* l1aWl, const float* l1abl, const float* l1aWr,
                     const float* l2cWl, const float* l2cbl, const float* l2cWr,
                     const float* l2aWl, const float* l2abl, const float* l2aWr,
                     const float* lhWl, const float* lhWr,
                     unsigned short* W1, float* b1,
                     unsigned short* W2, float* b2,
                     unsigned short* WH,
                     const int* __restrict__ dc, int Ec,
                     const int* __restrict__ da, int Ea,
                     const int* __restrict__ dh, int Eh,
                     int nbc, int nba, int totB, int* __restrict__ bcnt,
                     int nbHist, uint32_t* __restrict__ S1, uint32_t* __restrict__ SH) {
    __shared__ int lh[HB];
    const int b = blockIdx.x, tid = threadIdx.x;
    if (b < nbCvt) {
        int i = b * 256 + tid;
        const float* X; uint32_t* Y; int j;
        const int n80 = NP * 16;
        if (i < n80)                 { X = x_p; Y = xb_p; j = i; }
        else if (i < n80 + NA * 16)  { X = x_a; Y = xb_a; j = i - n80; }
        else return;
        float4 v0 = *(const float4*)(X + (size_t)j * 8);
        float4 v1 = *(const float4*)(X + (size_t)j * 8 + 4);
        uint4 o;
        o.x = cvtpk(v0.x, v0.y); o.y = cvtpk(v0.z, v0.w);
        o.z = cvtpk(v1.x, v1.y); o.w = cvtpk(v1.z, v1.w);
        *(uint4*)(Y + (size_t)j * 4) = o;
    } else if (b < nbCvt + 192) {
        const int bid = b - nbCvt;
        if (bid < 64) {
            int i = bid * 256 + tid;
            W1[i]         = bf16_1(0.5f * l1cWl[i]);
            W1[16384 + i] = bf16_1(0.5f * l1aWl[i]);
            W1[32768 + i] = bf16_1(0.5f * (l1cWr[i] + l1aWr[i]));
            if (i < 128) b1[i] = 0.5f * (l1cbl[i] + l1abl[i]);
        } else if (bid < 128) {
            int i = (bid - 64) * 256 + tid;
            W2[i]         = bf16_1(0.5f * l2cWl[i]);
            W2[16384 + i] = bf16_1(0.5f * l2aWl[i]);
            W2[32768 + i] = bf16_1(0.5f * (l2cWr[i] + l2aWr[i]));
            if (i < 128) b2[i] = 0.5f * (l2cbl[i] + l2abl[i]);
        } else {
            int i = (bid - 128) * 256 + tid;
            WH[i]         = bf16_1(lhWl[i]);
            WH[16384 + i] = bf16_1(lhWr[i]);
        }
    } else if (b < nbCvt + 192 + nbHist) {
        // bucket histogram via LDS
        const int hb = b - nbCvt - 192;
        for (int k = tid; k < HB; k += 256) lh[k] = 0;
        __syncthreads();
        const int Etot = Ec + Ea + Eh;
        const int start = hb * 16384;
        const int end = min(start + 16384, Etot);
        for (int i = start + tid; i < end; i += 256) {
            int bin;
            if (i < Ec)            bin = dc[i] >> 7;
            else if (i < Ec + Ea)  bin = nbc + (da[i - Ec] >> 7);
            else                   bin = nbc + nba + (dh[i - Ec - Ea] >> 7);
            atomicAdd(&lh[bin], 1);
        }
        __syncthreads();
        for (int k = tid; k < totB; k += 256) {
            int v = lh[k];
            if (v) atomicAdd(&bcnt[k], v);
        }
    } else {
        // zero rows at index N of each gathered table
        const int w = tid & 63, which = tid >> 6;
        uint32_t* dst = (which == 0) ? xb_p + (size_t)NP * 64
                      : (which == 1) ? xb_a + (size_t)NA * 64
                      : (which == 2) ? S1 + (size_t)NP * 64
                                     : SH + (size_t)NA * 64;
        dst[w] = 0;
    }
}

// ======================= aggregation =======================

__device__ __forceinline__ void acc8(float* a, uint4 q) {
    a[0] += blo(q.x); a[1] += bhi(q.x);
    a[2] += blo(q.y); a[3] += bhi(q.y);
    a[4] += blo(q.z); a[5] += bhi(q.z);
    a[6] += blo(q.w); a[7] += bhi(q.w);
}

// padded quad-edge gather mean: 1 wave/row; uniform quad count (no
// predication); 32-bit byte-offset gathers; cvt_pk epilogue.
__device__ __forceinline__ void agg_row(const uint32_t* __restrict__ X,
                                        const uint32_t* __restrict__ offp,
                                        const int* __restrict__ col,
                                        uint32_t* __restrict__ Y, int row) {
    const int lane = threadIdx.x & 63;
    const int g = lane >> 4, t = lane & 15;
    const uint32_t pk = offp[row];
    int e = (int)(pk & 0x3FFFFFu);
    const int deg = (int)(pk >> 22);
    int nq = (deg + 3) >> 2;
    const char* Xc = (const char*)X;
    const uint32_t bo = (uint32_t)(t << 4);
    float A0[8] = {0.f, 0.f, 0.f, 0.f, 0.f, 0.f, 0.f, 0.f};
    float A1[8] = {0.f, 0.f, 0.f, 0.f, 0.f, 0.f, 0.f, 0.f};
    while (nq >= 2) {
        int sA = col[e + g];
        int sB = col[e + 4 + g];
        uint4 qA = *(const uint4*)(Xc + (((uint32_t)sA << 8) + bo));
        uint4 qB = *(const uint4*)(Xc + (((uint32_t)sB << 8) + bo));
        acc8(A0, qA); acc8(A1, qB);
        e += 8; nq -= 2;
    }
    if (nq) {
        int sA = col[e + g];
        uint4 qA = *(const uint4*)(Xc + (((uint32_t)sA << 8) + bo));
        acc8(A0, qA);
    }
    const float inv = 1.0f / (float)(deg > 0 ? deg : 1);
    float a[8];
#pragma unroll
    for (int j = 0; j < 8; ++j) {
        float v = A0[j] + A1[j];
        v += __shfl_xor(v, 16, 64);
        v += __shfl_xor(v, 32, 64);
        a[j] = v * inv;
    }
    if (g == 0) {
        uint4 o;
        o.x = cvtpk(a[0], a[1]); o.y = cvtpk(a[2], a[3]);
        o.z = cvtpk(a[4], a[5]); o.w = cvtpk(a[6], a[7]);
        *(uint4*)(Y + (size_t)row * 64 + (t << 2)) = o;
    }
}

__global__ __launch_bounds__(256)
void agg_l1_kernel(const uint32_t* __restrict__ xb_p, const uint32_t* __restrict__ xb_a,
                   const uint32_t* __restrict__ off_c, const int* __restrict__ col_c,
                   const uint32_t* __restrict__ off_a, const int* __restrict__ col_a,
                   const uint32_t* __restrict__ off_h, const int* __restrict__ col_h,
                   uint32_t* __restrict__ S1, uint32_t* __restrict__ S2,
                   uint32_t* __restrict__ SH, int NP, int NA) {
    int gw = (blockIdx.x * 256 + threadIdx.x) >> 6;
    if (gw < NP)               agg_row(xb_p, off_c, col_c, S1, gw);
    else if (gw < 2 * NP)      agg_row(xb_a, off_a, col_a, S2, gw - NP);
    else if (gw < 2 * NP + NA) agg_row(xb_p, off_h, col_h, SH, gw - 2 * NP);
}

__global__ __launch_bounds__(256)
void agg_l2_kernel(const uint32_t* __restrict__ P1, const uint32_t* __restrict__ A1,
                   const uint32_t* __restrict__ off_c, const int* __restrict__ col_c,
                   const uint32_t* __restrict__ off_a, const int* __restrict__ col_a,
                   uint32_t* __restrict__ S2, uint32_t* __restrict__ S3, int NP) {
    int gw = (blockIdx.x * 256 + threadIdx.x) >> 6;
    if (gw < NP)          agg_row(P1, off_c, col_c, S2, gw);
    else if (gw < 2 * NP) agg_row(A1, off_a, col_a, S3, gw - NP);
}

// ======================= transform (bf16 MFMA, single-W) ====================

template <int PAIRS>
__device__ __forceinline__ void transform_body(
        int blk, const unsigned short* A0, const unsigned short* A1,
        const unsigned short* A2,
        const unsigned short* __restrict__ W,
        const float* __restrict__ bias, unsigned short* Y, int N,
        unsigned short* Bs) {
    const int tid  = threadIdx.x;
    const int l    = tid & 63;
    const int wv   = tid >> 6;
    const int lrow = l & 15;
    const int lkg  = l >> 4;
    const int rw   = blk * 128 + wv * 32;

    f32x4 acc0[8], acc1[8];
#pragma unroll
    for (int t = 0; t < 8; ++t) {
        acc0[t] = (f32x4){0.f, 0.f, 0.f, 0.f};
        acc1[t] = (f32x4){0.f, 0.f, 0.f, 0.f};
    }

    int arow0 = rw + lrow;      if (arow0 >= N) arow0 = N - 1;
    int arow1 = rw + 16 + lrow; if (arow1 >= N) arow1 = N - 1;
    const int kbase = lkg << 3;
    const int cb    = lkg << 4;

#pragma unroll 1
    for (int p = 0; p < PAIRS; ++p) {
        {
            const char* src = (const char*)(W + (p << 14));
#pragma unroll
            for (int it = 0; it < 8; ++it) {
                const int L = it * 4096 + tid * 16;
                const int j = L >> 8;
                const int g = (j << 8) + ((L & 255) ^ ((j & 7) << 4));
                gload_lds16(src + g, (char*)Bs + L);
            }
        }
        __syncthreads();
        const unsigned short* A = (p == 0) ? A0 : (p == 1) ? A1 : A2;
#pragma unroll
        for (int kc = 0; kc < 4; ++kc) {
            bf16x8 a0 = *(const bf16x8*)(A + (size_t)arow0 * 128 + kc * 32 + kbase);
            bf16x8 a1 = *(const bf16x8*)(A + (size_t)arow1 * 128 + kc * 32 + kbase);
            const int cbk = kc * 64 + cb;
#pragma unroll
            for (int t = 0; t < 8; ++t) {
                const int jt   = (t << 4) + lrow;
                const int addr = (jt << 8) + (cbk ^ ((jt & 7) << 4));
                bf16x8 bh = *(const bf16x8*)((const char*)Bs + addr);
                acc0[t] = mfma16(a0, bh, acc0[t]);
                acc1[t] = mfma16(a1, bh, acc1[t]);
            }
        }
        __syncthreads();
    }
#pragma unroll
    for (int t = 0; t < 8; ++t) {
        const int c = t * 16 + lrow;
        const float bv = bias[c];
#pragma unroll
        for (int r = 0; r < 4; ++r) {
            int row0 = rw + (lkg << 2) + r;
            if (row0 < N)
                Y[(size_t)row0 * 128 + c] = bf16_1(fmaxf(acc0[t][r] + bv, 0.f));
            int row1 = row0 + 16;
            if (row1 < N)
                Y[(size_t)row1 * 128 + c] = bf16_1(fmaxf(acc1[t][r] + bv, 0.f));
        }
    }
}

__global__ __launch_bounds__(256, 2)
void transform_l1_kernel(const unsigned short* S1, const unsigned short* S2,
                         const unsigned short* xb_p,
                         const unsigned short* __restrict__ W1,
                         const float* __restrict__ b1,
                         const unsigned short* SH, const unsigned short* xb_a,
                         const unsigned short* __restrict__ WH,
                         const float* __restrict__ bh,
                         unsigned short* P1out, unsigned short* A1out,
                         int NP, int NA, int nbP) {
    __shared__ unsigned short Bs[128 * 128];   // 32 KB
    if ((int)blockIdx.x < nbP)
        transform_body<3>(blockIdx.x, S1, S2, xb_p, W1, b1, P1out, NP, Bs);
    else
        transform_body<2>(blockIdx.x - nbP, SH, xb_a, nullptr, WH, bh,
                          A1out, NA, Bs);
}

// transform_p2 with FUSED classifier head: p2 = relu(sum_p A_p@W_p^T + b)
// stays in registers; out[row][cls] = p2[row,:] . linW[cls,:] + linb[cls]
// via LDS-staged linW and a 16-lane shfl_xor reduce. No p2 store.
__global__ __launch_bounds__(256, 2)
void transform_p2_head_kernel(const unsigned short* A0, const unsigned short* A1,
                              const unsigned short* A2,
                              const unsigned short* __restrict__ W,
                              const float* __restrict__ bias,
                              const float* __restrict__ linW,
                              const float* __restrict__ linb,
                              float* __restrict__ out, int N) {
    __shared__ unsigned short Bs[128 * 128];   // 32 KB
    __shared__ float lwd[1024];   // linW [8][128]
    __shared__ float lbd[8];
    const int tid  = threadIdx.x;
    const int l    = tid & 63;
    const int wv   = tid >> 6;
    const int lrow = l & 15;
    const int lkg  = l >> 4;
    const int rw   = (int)blockIdx.x * 128 + wv * 32;

    for (int i = tid; i < 1024; i += 256) lwd[i] = linW[i];
    if (tid < 8) lbd[tid] = linb[tid];

    f32x4 acc0[8], acc1[8];
#pragma unroll
    for (int t = 0; t < 8; ++t) {
        acc0[t] = (f32x4){0.f, 0.f, 0.f, 0.f};
        acc1[t] = (f32x4){0.f, 0.f, 0.f, 0.f};
    }

    int arow0 = rw + lrow;      if (arow0 >= N) arow0 = N - 1;
    int arow1 = rw + 16 + lrow; if (arow1 >= N) arow1 = N - 1;
    const int kbase = lkg << 3;
    const int cb    = lkg << 4;

#pragma unroll 1
    for (int p = 0; p < 3; ++p) {
        {
            const char* src = (const char*)(W + (p << 14));
#pragma unroll
            for (int it = 0; it < 8; ++it) {
                const int L = it * 4096 + tid * 16;
                const int j = L >> 8;
                const int g = (j << 8) + ((L & 255) ^ ((j & 7) << 4));
                gload_lds16(src + g, (char*)Bs + L);
            }
        }
        __syncthreads();
        const unsigned short* A = (p == 0) ? A0 : (p == 1) ? A1 : A2;
#pragma unroll
        for (int kc = 0; kc < 4; ++kc) {
            bf16x8 a0 = *(const bf16x8*)(A + (size_t)arow0 * 128 + kc * 32 + kbase);
            bf16x8 a1 = *(const bf16x8*)(A + (size_t)arow1 * 128 + kc * 32 + kbase);
            const int cbk = kc * 64 + cb;
#pragma unroll
            for (int t = 0; t < 8; ++t) {
                const int jt   = (t << 4) + lrow;
                const int addr = (jt << 8) + (cbk ^ ((jt & 7) << 4));
                bf16x8 bh = *(const bf16x8*)((const char*)Bs + addr);
                acc0[t] = mfma16(a0, bh, acc0[t]);
                acc1[t] = mfma16(a1, bh, acc1[t]);
            }
        }
        __syncthreads();
    }
    // bias + relu in-register -> p2
#pragma unroll
    for (int t = 0; t < 8; ++t) {
        const float bv = bias[t * 16 + lrow];
#pragma unroll
        for (int r = 0; r < 4; ++r) {
            acc0[t][r] = fmaxf(acc0[t][r] + bv, 0.f);
            acc1[t][r] = fmaxf(acc1[t][r] + bv, 0.f);
        }
    }
    // head: per class, dot owned cols then reduce across the 16-lane group
    float o0[4], o1[4];
#pragma unroll
    for (int cls = 0; cls < 8; ++cls) {
        float wvv[8];
#pragma unroll
        for (int t = 0; t < 8; ++t) wvv[t] = lwd[cls * 128 + t * 16 + lrow];
#pragma unroll
        for (int r = 0; r < 4; ++r) {
            float s0 = 0.f, s1 = 0.f;
#pragma unroll
            for (int t = 0; t < 8; ++t) {
                s0 += acc0[t][r] * wvv[t];
                s1 += acc1[t][r] * wvv[t];
            }
            s0 += __shfl_xor(s0, 1, 64); s0 += __shfl_xor(s0, 2, 64);
            s0 += __shfl_xor(s0, 4, 64); s0 += __shfl_xor(s0, 8, 64);
            s1 += __shfl_xor(s1, 1, 64); s1 += __shfl_xor(s1, 2, 64);
            s1 += __shfl_xor(s1, 4, 64); s1 += __shfl_xor(s1, 8, 64);
            if (lrow == cls) { o0[r] = s0; o1[r] = s1; }
        }
    }
    if (lrow < 8) {
        const float lbv = lbd[lrow];
#pragma unroll
        for (int r = 0; r < 4; ++r) {
            int row0 = rw + (lkg << 2) + r;
            if (row0 < N) out[(size_t)row0 * 8 + lrow] = o0[r] + lbv;
            int row1 = row0 + 16;
            if (row1 < N) out[(size_t)row1 * 8 + lrow] = o1[r] + lbv;
        }
    }
}

extern "C" void kernel_launch(void* const* d_in, const int* in_sizes, int n_in,
                              void* d_out, int out_size, void* d_ws, size_t ws_size,
                              hipStream_t stream) {
    const float* x_p = (const float*)d_in[0];
    const float* x_a = (const float*)d_in[1];
    const int* c_src = (const int*)d_in[2];
    const int* c_dst = (const int*)d_in[3];
    const int* a_src = (const int*)d_in[4];
    const int* a_dst = (const int*)d_in[5];
    const int* h_src = (const int*)d_in[6];
    const int* h_dst = (const int*)d_in[7];
    const float* l1c_Wl = (const float*)d_in[8];
    const float* l1c_bl = (const float*)d_in[9];
    const float* l1c_Wr = (const float*)d_in[10];
    const float* l1a_Wl = (const float*)d_in[11];
    const float* l1a_bl = (const float*)d_in[12];
    const float* l1a_Wr = (const float*)d_in[13];
    const float* l1h_Wl = (const float*)d_in[14];
    const float* l1h_bl = (const float*)d_in[15];
    const float* l1h_Wr = (const float*)d_in[16];
    const float* l2c_Wl = (const float*)d_in[17];
    const float* l2c_bl = (const float*)d_in[18];
    const float* l2c_Wr = (const float*)d_in[19];
    const float* l2a_Wl = (const float*)d_in[20];
    const float* l2a_bl = (const float*)d_in[21];
    const float* l2a_Wr = (const float*)d_in[22];
    const float* linW   = (const float*)d_in[26];
    const float* linb   = (const float*)d_in[27];

    const int NP = in_sizes[0] / 128;
    const int NA = in_sizes[1] / 128;
    const int Ec = in_sizes[2];
    const int Ea = in_sizes[4];
    const int Eh = in_sizes[6];
    const int Etot = Ec + Ea + Eh;

    const int nbc = (NP + 127) >> 7;
    const int nba = (NP + 127) >> 7;
    const int nbh = (NA + 127) >> 7;
    const int totB = nbc + nba + nbh;
    if (totB > HB) return;

    // ---- carve workspace ----
    char* base = (char*)d_ws;
    size_t cur = 0;
    auto carve = [&](size_t bytes) -> char* {
        char* p = base + cur;
        cur = (cur + bytes + 255) & ~(size_t)255;
        return p;
    };
    uint32_t* xb_p = (uint32_t*)carve((size_t)(NP + 1) * 128 * 2);  // +zero row
    uint32_t* xb_a = (uint32_t*)carve((size_t)(NA + 1) * 128 * 2);  // +zero row
    uint32_t* S1 = (uint32_t*)carve((size_t)(NP + 1) * 128 * 2);    // +zero row
    uint32_t* S2 = (uint32_t*)carve((size_t)NP * 128 * 2);
    uint32_t* S3 = (uint32_t*)carve((size_t)NP * 128 * 2);
    uint32_t* SH = (uint32_t*)carve((size_t)(NA + 1) * 128 * 2);    // +zero row
    unsigned short* W1 = (unsigned short*)carve(3 * 16384 * 2);
    unsigned short* W2 = (unsigned short*)carve(3 * 16384 * 2);
    unsigned short* WH = (unsigned short*)carve(2 * 16384 * 2);
    float* b1 = (float*)carve(512);
    float* b2 = (float*)carve(512);
    uint32_t* off_c = (uint32_t*)carve((size_t)NP * 4);
    uint32_t* off_a = (uint32_t*)carve((size_t)NP * 4);
    uint32_t* off_h = (uint32_t*)carve((size_t)NA * 4);
    int* colAll = (int*)carve(((size_t)Etot + 384 * (size_t)totB) * 4);
    uint32_t* pairs = (uint32_t*)carve((size_t)Etot * 4);
    int* gboff = (int*)carve((size_t)(totB + 1) * 4);
    int* bcur  = (int*)carve((size_t)totB * 4);
    int* bcnt  = (int*)carve((size_t)totB * 4);
    if (cur > ws_size) return;

    const int EcPad = Ec + 384 * nbc;
    const int EaPad = Ea + 384 * nba;
    int* col_c = colAll;
    int* col_a = colAll + EcPad;
    int* col_h = colAll + EcPad + EaPad;

    // ---- prologue: memset + {cvt, prep, hist, zero-rows} in one dispatch ----
    hipMemsetAsync(bcnt, 0, (size_t)totB * 4, stream);
    const int nbCvt = ((NP + NA) * 16 + 255) / 256;
    const int nbHist = (Etot + 16383) / 16384;
    prologue_kernel<<<nbCvt + 192 + nbHist + 1, 256, 0, stream>>>(
        x_p, x_a, xb_p, xb_a, NP, NA, nbCvt,
        l1c_Wl, l1c_bl, l1c_Wr, l1a_Wl, l1a_bl, l1a_Wr,
        l2c_Wl, l2c_bl, l2c_Wr, l2a_Wl, l2a_bl, l2a_Wr,
        l1h_Wl, l1h_Wr, W1, b1, W2, b2, WH,
        c_dst, Ec, a_dst, Ea, h_dst, Eh, nbc, nba, totB, bcnt, nbHist, S1, SH);

    // ---- CSR build (padded, packed off|deg, packed uint32 pairs) ----
    scan_fast_kernel<<<1, 1024, 0, stream>>>(bcnt, nbc, nba, nbh, Ec, Ea, Eh,
                                             gboff, bcur);
    partition_kernel<<<(Etot + 2047) / 2048, 256, 0, stream>>>(
        c_src, c_dst, Ec, a_src, a_dst, Ea, h_src, h_dst, Eh,
        nbc, nba, totB, bcur, pairs);
    bucket_build_kernel<<<totB, 256, 0, stream>>>(
        pairs, gboff, nbc, nba, NP, NA, Ec, Ea,
        off_c, off_a, off_h, col_c, col_a, col_h);

    // ---- layer 1 ----
    const int rows_l1 = 2 * NP + NA;
    agg_l1_kernel<<<(rows_l1 + 3) / 4, 256, 0, stream>>>(
        xb_p, xb_a, off_c, col_c, off_a, col_a, off_h, col_h, S1, S2, SH, NP, NA);
    const int nbP = (NP + 127) / 128;
    const int nbA = (NA + 127) / 128;
    transform_l1_kernel<<<nbP + nbA, 256, 0, stream>>>(
        (const unsigned short*)S1, (const unsigned short*)S2,
        (const unsigned short*)xb_p, W1, b1,
        (const unsigned short*)SH, (const unsigned short*)xb_a, WH, l1h_bl,
        (unsigned short*)S1, (unsigned short*)SH, NP, NA, nbP);

    // ---- layer 2 (head fused into transform) ----
    agg_l2_kernel<<<(2 * NP + 3) / 4, 256, 0, stream>>>(
        S1, SH, off_c, col_c, off_a, col_a, S2, S3, NP);
    transform_p2_head_kernel<<<nbP, 256, 0, stream>>>(
        (const unsigned short*)S2, (const unsigned short*)S3,
        (const unsigned short*)S1, W2, b2,
        linW, linb, (float*)d_out, NP);
}